// Round 2
// baseline (1026.317 us; speedup 1.0000x reference)
//
#include <hip/hip_runtime.h>
#include <math.h>

#define NN 100000
#define NE 3200000
#define F_IN 64
#define HID 16
#define NC 4

#define SZB 128            // nodes per bucket
#define NB 782             // ceil(NN / SZB)
#define CHUNK 16384        // edges per block in count/bin passes
#define NCHUNK 196         // ceil(NE / CHUNK)

// ---------- Pass A: global histogram of edges per bucket ----------
__global__ __launch_bounds__(1024) void k_count(const int* __restrict__ col,
                                                int* __restrict__ hist) {
    __shared__ int h[NB];
    for (int i = threadIdx.x; i < NB; i += 1024) h[i] = 0;
    __syncthreads();
    int e0 = blockIdx.x * CHUNK;
    int e1 = min(e0 + CHUNK, NE);
    for (int i = e0 + threadIdx.x; i < e1; i += 1024)
        atomicAdd(&h[col[i] >> 7], 1);
    __syncthreads();
    for (int i = threadIdx.x; i < NB; i += 1024)
        if (h[i]) atomicAdd(&hist[i], h[i]);
}

// ---------- Pass B: exclusive scan (tiny, single thread) ----------
__global__ void k_scan(const int* __restrict__ hist, int* __restrict__ start,
                       int* __restrict__ cursor) {
    if (threadIdx.x == 0 && blockIdx.x == 0) {
        int s = 0;
        for (int i = 0; i < NB; i++) {
            start[i] = s; cursor[i] = s; s += hist[i];
        }
        start[NB] = s;
    }
}

// ---------- Pass C: scatter edges into bucket-contiguous order ----------
// bin[pos] = { (row<<7)|col_local , bits(ew) }
__global__ __launch_bounds__(1024) void k_bin(const int* __restrict__ row,
                                              const int* __restrict__ col,
                                              const float* __restrict__ ew,
                                              int* __restrict__ cursor,
                                              uint2* __restrict__ bin) {
    __shared__ int h[NB];
    __shared__ int base[NB];
    for (int i = threadIdx.x; i < NB; i += 1024) h[i] = 0;
    __syncthreads();
    int e0 = blockIdx.x * CHUNK;
    int e1 = min(e0 + CHUNK, NE);
    for (int i = e0 + threadIdx.x; i < e1; i += 1024)
        atomicAdd(&h[col[i] >> 7], 1);
    __syncthreads();
    for (int i = threadIdx.x; i < NB; i += 1024) {
        int c = h[i];
        if (c) base[i] = atomicAdd(&cursor[i], c);
        h[i] = 0;
    }
    __syncthreads();
    for (int i = e0 + threadIdx.x; i < e1; i += 1024) {
        int c = col[i];
        int b = c >> 7;
        int off = atomicAdd(&h[b], 1);
        int pos = base[b] + off;
        bin[pos] = make_uint2(((unsigned)row[i] << 7) | (unsigned)(c & 127),
                              __float_as_uint(ew[i]));
    }
}

// ---------- Pass D: weighted degree per bucket (LDS), -> dinv ----------
__global__ __launch_bounds__(128) void k_deg(const uint2* __restrict__ bin,
                                             const int* __restrict__ start,
                                             float* __restrict__ dinv) {
    __shared__ float acc[SZB];
    int b = blockIdx.x;
    acc[threadIdx.x] = 1.0f;   // self-loop weight
    __syncthreads();
    int s = start[b], e = start[b + 1];
    for (int i = s + threadIdx.x; i < e; i += 128) {
        uint2 u = bin[i];
        atomicAdd(&acc[u.x & 127], __uint_as_float(u.y));
    }
    __syncthreads();
    int n = b * SZB + threadIdx.x;
    if (n < NN) {
        float d = acc[threadIdx.x];
        dinv[n] = d > 0.0f ? rsqrtf(d) : 0.0f;
    }
}

// ---------- Pass E: rewrite ew -> norm in binned order ----------
__global__ __launch_bounds__(256) void k_normk(uint2* __restrict__ bin,
                                               const int* __restrict__ start,
                                               const float* __restrict__ dinv) {
    int b = blockIdx.x;
    int s = start[b], e = start[b + 1];
    for (int i = s + threadIdx.x; i < e; i += 256) {
        uint2 u = bin[i];
        int r = u.x >> 7;
        int c = b * SZB + (u.x & 127);
        float nm = dinv[r] * __uint_as_float(u.y) * dinv[c];
        bin[i] = make_uint2(u.x, __float_as_uint(nm));
    }
}

// ---------- Transforms (t = act(in) @ W), weights in LDS ----------
__global__ __launch_bounds__(256) void k_xform1(const float* __restrict__ x,
                                                const float* __restrict__ W,
                                                float* __restrict__ t) {
    __shared__ float Ws[F_IN * HID];
    for (int i = threadIdx.x; i < F_IN * HID; i += 256) Ws[i] = W[i];
    __syncthreads();
    int n = blockIdx.x * blockDim.x + threadIdx.x;
    if (n >= NN) return;
    float acc[HID];
#pragma unroll
    for (int j = 0; j < HID; j++) acc[j] = 0.0f;
    const float4* xp = (const float4*)(x + (size_t)n * F_IN);
#pragma unroll
    for (int k4 = 0; k4 < F_IN / 4; k4++) {
        float4 v = xp[k4];
        int k = k4 * 4;
#pragma unroll
        for (int j = 0; j < HID; j++) {
            acc[j] += v.x * Ws[(k + 0) * HID + j];
            acc[j] += v.y * Ws[(k + 1) * HID + j];
            acc[j] += v.z * Ws[(k + 2) * HID + j];
            acc[j] += v.w * Ws[(k + 3) * HID + j];
        }
    }
#pragma unroll
    for (int j = 0; j < HID; j++) t[(size_t)n * HID + j] = acc[j];
}

template <int DOUT>
__global__ __launch_bounds__(256) void k_xform(const float* __restrict__ hin,
                                               const float* __restrict__ W,
                                               float* __restrict__ t) {
    __shared__ float Ws[HID * DOUT];
    for (int i = threadIdx.x; i < HID * DOUT; i += 256) Ws[i] = W[i];
    __syncthreads();
    int n = blockIdx.x * blockDim.x + threadIdx.x;
    if (n >= NN) return;
    float h[HID];
    const float4* hp = (const float4*)(hin + (size_t)n * HID);
#pragma unroll
    for (int k4 = 0; k4 < HID / 4; k4++) {
        float4 v = hp[k4];
        h[k4 * 4 + 0] = fmaxf(v.x, 0.0f);
        h[k4 * 4 + 1] = fmaxf(v.y, 0.0f);
        h[k4 * 4 + 2] = fmaxf(v.z, 0.0f);
        h[k4 * 4 + 3] = fmaxf(v.w, 0.0f);
    }
    float acc[DOUT];
#pragma unroll
    for (int j = 0; j < DOUT; j++) acc[j] = 0.0f;
#pragma unroll
    for (int k = 0; k < HID; k++)
#pragma unroll
        for (int j = 0; j < DOUT; j++) acc[j] += h[k] * Ws[k * DOUT + j];
#pragma unroll
    for (int j = 0; j < DOUT; j++) t[(size_t)n * DOUT + j] = acc[j];
}

// ---------- Aggregation: one block per bucket, LDS accumulate ----------
// out[n] = bias + dinv[n]^2 * t[n] + sum_{edges into n} norm * t[row]
template <int DOUT, int LOG>
__global__ __launch_bounds__(1024) void k_agg(const uint2* __restrict__ bin,
                                              const int* __restrict__ start,
                                              const float* __restrict__ t,
                                              const float* __restrict__ bias,
                                              const float* __restrict__ dinv,
                                              float* __restrict__ out) {
    __shared__ float acc[SZB * DOUT];
    for (int i = threadIdx.x; i < SZB * DOUT; i += 1024) acc[i] = 0.0f;
    __syncthreads();
    int b = blockIdx.x;
    int s = start[b], e = start[b + 1];
    int j = threadIdx.x & (DOUT - 1);
    int g = threadIdx.x >> LOG;
    const int GS = 1024 >> LOG;
    for (int i = s + g; i < e; i += GS) {
        uint2 u = bin[i];
        int r = u.x >> 7;
        int cl = u.x & 127;
        float v = __uint_as_float(u.y) * t[(size_t)r * DOUT + j];
        atomicAdd(&acc[cl * DOUT + j], v);
    }
    __syncthreads();
    for (int idx = threadIdx.x; idx < SZB * DOUT; idx += 1024) {
        int n = b * SZB + (idx >> LOG);
        int jj = idx & (DOUT - 1);
        if (n < NN) {
            float di = dinv[n];
            out[(size_t)n * DOUT + jj] =
                bias[jj] + di * di * t[(size_t)n * DOUT + jj] + acc[idx];
        }
    }
}

__global__ __launch_bounds__(256) void k_logsoftmax(float* __restrict__ out) {
    int n = blockIdx.x * blockDim.x + threadIdx.x;
    if (n >= NN) return;
    float4 v = ((float4*)out)[n];
    float m = fmaxf(fmaxf(v.x, v.y), fmaxf(v.z, v.w));
    float s = expf(v.x - m) + expf(v.y - m) + expf(v.z - m) + expf(v.w - m);
    float l = m + logf(s);
    ((float4*)out)[n] = make_float4(v.x - l, v.y - l, v.z - l, v.w - l);
}

extern "C" void kernel_launch(void* const* d_in, const int* in_sizes, int n_in,
                              void* d_out, int out_size, void* d_ws, size_t ws_size,
                              hipStream_t stream) {
    const float* x  = (const float*)d_in[0];
    const int*   ei = (const int*)d_in[1];   // [2, E]: row then col
    const float* ew = (const float*)d_in[2];
    const float* W1 = (const float*)d_in[3];
    const float* b1 = (const float*)d_in[4];
    const float* W3 = (const float*)d_in[5];
    const float* b3 = (const float*)d_in[6];
    const float* W2 = (const float*)d_in[7];
    const float* b2 = (const float*)d_in[8];
    float* out = (float*)d_out;

    const int* row = ei;
    const int* col = ei + NE;

    // workspace layout (bytes):
    char* ws = (char*)d_ws;
    float* dinv  = (float*)ws;                                 // NN floats = 400,000 B
    uint2* bin   = (uint2*)(ws + 400000);                      // NE uint2 = 25.6 MB
    float* A     = (float*)(ws + 400000 + (size_t)NE * 8);     // N*16 = 6.4 MB
    float* B     = A + (size_t)NN * HID;                       // N*16 = 6.4 MB
    int*   hist  = (int*)(B + (size_t)NN * HID);               // NB
    int*   start = hist + NB;                                  // NB+1
    int*   curs  = start + NB + 1;                             // NB

    hipMemsetAsync(hist, 0, NB * sizeof(int), stream);

    // Build binned edge structure
    k_count<<<NCHUNK, 1024, 0, stream>>>(col, hist);
    k_scan<<<1, 64, 0, stream>>>(hist, start, curs);
    k_bin<<<NCHUNK, 1024, 0, stream>>>(row, col, ew, curs, bin);

    // Degree -> dinv, then norm in place
    k_deg<<<NB, 128, 0, stream>>>(bin, start, dinv);
    k_normk<<<NB, 256, 0, stream>>>(bin, start, dinv);

    int gN = (NN + 255) / 256;

    // Layer 1
    k_xform1<<<gN, 256, 0, stream>>>(x, W1, A);
    k_agg<HID, 4><<<NB, 1024, 0, stream>>>(bin, start, A, b1, dinv, B);
    // Layer 2
    k_xform<HID><<<gN, 256, 0, stream>>>(B, W3, A);
    k_agg<HID, 4><<<NB, 1024, 0, stream>>>(bin, start, A, b3, dinv, B);
    // Layer 3
    k_xform<NC><<<gN, 256, 0, stream>>>(B, W2, A);
    k_agg<NC, 2><<<NB, 1024, 0, stream>>>(bin, start, A, b2, dinv, out);

    k_logsoftmax<<<gN, 256, 0, stream>>>(out);
}

// Round 3
// 390.983 us; speedup vs baseline: 2.6250x; 2.6250x over previous
//
#include <hip/hip_runtime.h>
#include <math.h>

#define NN 100000
#define NE 3200000
#define F_IN 64
#define HID 16
#define NC 4

#define SZB 128            // nodes per bucket
#define NB 782             // ceil(NN / SZB)
#define CHUNK 16384        // edges per block in count/bin passes
#define NCHUNK 196         // ceil(NE / CHUNK)

// ---------- Pass A: global histogram of edges per bucket ----------
__global__ __launch_bounds__(1024) void k_count(const int* __restrict__ col,
                                                int* __restrict__ hist) {
    __shared__ int h[NB];
    for (int i = threadIdx.x; i < NB; i += 1024) h[i] = 0;
    __syncthreads();
    int e0 = blockIdx.x * CHUNK;
    int e1 = min(e0 + CHUNK, NE);
    for (int i = e0 + threadIdx.x; i < e1; i += 1024)
        atomicAdd(&h[col[i] >> 7], 1);
    __syncthreads();
    for (int i = threadIdx.x; i < NB; i += 1024)
        if (h[i]) atomicAdd(&hist[i], h[i]);
}

// ---------- Pass B: block-parallel exclusive scan over NB buckets ----------
__global__ __launch_bounds__(1024) void k_scan(const int* __restrict__ hist,
                                               int* __restrict__ start,
                                               int* __restrict__ cursor,
                                               int* __restrict__ nodeptr) {
    __shared__ int a[1024];
    int tid = threadIdx.x;
    int h0 = (tid < NB) ? hist[tid] : 0;
    a[tid] = h0;
    for (int off = 1; off < 1024; off <<= 1) {
        __syncthreads();
        int v = (tid >= off) ? a[tid - off] : 0;
        __syncthreads();
        a[tid] += v;
    }
    __syncthreads();
    if (tid < NB) {
        int ex = a[tid] - h0;            // exclusive prefix
        start[tid] = ex;
        cursor[tid] = ex;
    }
    if (tid == NB - 1) start[NB] = a[tid];
    if (tid == 0) nodeptr[NN] = NE;
}

// ---------- Pass C: scatter edges into bucket-contiguous order ----------
// bin[pos] = { (row<<7)|col_local , bits(ew) }
__global__ __launch_bounds__(1024) void k_bin(const int* __restrict__ row,
                                              const int* __restrict__ col,
                                              const float* __restrict__ ew,
                                              int* __restrict__ cursor,
                                              uint2* __restrict__ bin) {
    __shared__ int h[NB];
    __shared__ int base[NB];
    for (int i = threadIdx.x; i < NB; i += 1024) h[i] = 0;
    __syncthreads();
    int e0 = blockIdx.x * CHUNK;
    int e1 = min(e0 + CHUNK, NE);
    for (int i = e0 + threadIdx.x; i < e1; i += 1024)
        atomicAdd(&h[col[i] >> 7], 1);
    __syncthreads();
    for (int i = threadIdx.x; i < NB; i += 1024) {
        int c = h[i];
        if (c) base[i] = atomicAdd(&cursor[i], c);
        h[i] = 0;
    }
    __syncthreads();
    for (int i = e0 + threadIdx.x; i < e1; i += 1024) {
        int c = col[i];
        int b = c >> 7;
        int off = atomicAdd(&h[b], 1);
        int pos = base[b] + off;
        bin[pos] = make_uint2(((unsigned)row[i] << 7) | (unsigned)(c & 127),
                              __float_as_uint(ew[i]));
    }
}

// ---------- Pass D: within-bucket counting sort -> full CSR ----------
// Also emits nodeptr[n] and dinv[n] (weighted degree incl. self-loop).
__global__ __launch_bounds__(1024) void k_sort(const uint2* __restrict__ bin,
                                               const int* __restrict__ start,
                                               unsigned* __restrict__ skey,
                                               float* __restrict__ sval,
                                               int* __restrict__ nodeptr,
                                               float* __restrict__ dinv) {
    __shared__ int cnt[SZB];
    __shared__ float wdeg[SZB];
    __shared__ int cur[SZB];
    int b = blockIdx.x, tid = threadIdx.x;
    if (tid < SZB) { cnt[tid] = 0; wdeg[tid] = 0.0f; }
    __syncthreads();
    int s = start[b], e = start[b + 1];
    for (int i = s + tid; i < e; i += 1024) {
        uint2 u = bin[i];
        int cl = u.x & 127;
        atomicAdd(&cnt[cl], 1);
        atomicAdd(&wdeg[cl], __uint_as_float(u.y));
    }
    __syncthreads();
    if (tid < SZB) {
        int acc = 0;
        for (int i = 0; i < tid; i++) acc += cnt[i];   // tiny serial prefix
        cur[tid] = acc;
        int n = b * SZB + tid;
        if (n < NN) {
            nodeptr[n] = s + acc;
            dinv[n] = rsqrtf(1.0f + wdeg[tid]);        // deg >= 1 always
        }
    }
    __syncthreads();
    for (int i = s + tid; i < e; i += 1024) {
        uint2 u = bin[i];
        int cl = u.x & 127;
        int pos = s + atomicAdd(&cur[cl], 1);
        skey[pos] = u.x >> 7;                          // plain row index
        sval[pos] = __uint_as_float(u.y);              // raw edge weight
    }
}

// ---------- Transforms: tt = dinv * (act(in) @ W), weights in LDS ----------
__global__ __launch_bounds__(256) void k_xform1(const float* __restrict__ x,
                                                const float* __restrict__ W,
                                                const float* __restrict__ dinv,
                                                float* __restrict__ tt) {
    __shared__ float Ws[F_IN * HID];
    for (int i = threadIdx.x; i < F_IN * HID; i += 256) Ws[i] = W[i];
    __syncthreads();
    int n = blockIdx.x * blockDim.x + threadIdx.x;
    if (n >= NN) return;
    float acc[HID];
#pragma unroll
    for (int j = 0; j < HID; j++) acc[j] = 0.0f;
    const float4* xp = (const float4*)(x + (size_t)n * F_IN);
#pragma unroll
    for (int k4 = 0; k4 < F_IN / 4; k4++) {
        float4 v = xp[k4];
        int k = k4 * 4;
#pragma unroll
        for (int j = 0; j < HID; j++) {
            acc[j] += v.x * Ws[(k + 0) * HID + j];
            acc[j] += v.y * Ws[(k + 1) * HID + j];
            acc[j] += v.z * Ws[(k + 2) * HID + j];
            acc[j] += v.w * Ws[(k + 3) * HID + j];
        }
    }
    float di = dinv[n];
#pragma unroll
    for (int j = 0; j < HID; j++) tt[(size_t)n * HID + j] = di * acc[j];
}

template <int DOUT>
__global__ __launch_bounds__(256) void k_xform(const float* __restrict__ hin,
                                               const float* __restrict__ W,
                                               const float* __restrict__ dinv,
                                               float* __restrict__ tt) {
    __shared__ float Ws[HID * DOUT];
    for (int i = threadIdx.x; i < HID * DOUT; i += 256) Ws[i] = W[i];
    __syncthreads();
    int n = blockIdx.x * blockDim.x + threadIdx.x;
    if (n >= NN) return;
    float h[HID];
    const float4* hp = (const float4*)(hin + (size_t)n * HID);
#pragma unroll
    for (int k4 = 0; k4 < HID / 4; k4++) {
        float4 v = hp[k4];
        h[k4 * 4 + 0] = fmaxf(v.x, 0.0f);
        h[k4 * 4 + 1] = fmaxf(v.y, 0.0f);
        h[k4 * 4 + 2] = fmaxf(v.z, 0.0f);
        h[k4 * 4 + 3] = fmaxf(v.w, 0.0f);
    }
    float acc[DOUT];
#pragma unroll
    for (int j = 0; j < DOUT; j++) acc[j] = 0.0f;
#pragma unroll
    for (int k = 0; k < HID; k++)
#pragma unroll
        for (int j = 0; j < DOUT; j++) acc[j] += h[k] * Ws[k * DOUT + j];
    float di = dinv[n];
#pragma unroll
    for (int j = 0; j < DOUT; j++) tt[(size_t)n * DOUT + j] = di * acc[j];
}

// ---------- CSR aggregation, 16 lanes per node, zero atomics ----------
// out[n][j] = bias[j] + dinv[n] * ( sum_e ew_e * tt[row_e][j] + tt[n][j] )
__global__ __launch_bounds__(256) void k_agg16(const unsigned* __restrict__ skey,
                                               const float* __restrict__ sval,
                                               const int* __restrict__ nodeptr,
                                               const float* __restrict__ tt,
                                               const float* __restrict__ bias,
                                               const float* __restrict__ dinv,
                                               float* __restrict__ out) {
    int tid = blockIdx.x * 256 + threadIdx.x;
    int n = tid >> 4;
    int j = tid & 15;
    if (n >= NN) return;
    int e0 = nodeptr[n];
    int e1 = nodeptr[n + 1];
    float acc = 0.0f;
    for (int base = e0; base < e1; base += 16) {
        int idx = base + j;
        int key = 0; float w = 0.0f;
        if (idx < e1) { key = (int)skey[idx]; w = sval[idx]; }
        int cnt = e1 - base;
        if (cnt >= 16) {
#pragma unroll
            for (int q = 0; q < 16; q++) {
                int r = __shfl(key, q, 16);
                float ww = __shfl(w, q, 16);
                acc += ww * tt[((size_t)r << 4) + j];
            }
        } else {
            for (int q = 0; q < cnt; q++) {
                int r = __shfl(key, q, 16);
                float ww = __shfl(w, q, 16);
                acc += ww * tt[((size_t)r << 4) + j];
            }
        }
    }
    float di = dinv[n];
    out[((size_t)n << 4) + j] = bias[j] + di * (acc + tt[((size_t)n << 4) + j]);
}

// ---------- Final CSR aggregation (4 feats) + fused log-softmax ----------
__global__ __launch_bounds__(256) void k_agg4sm(const unsigned* __restrict__ skey,
                                                const float* __restrict__ sval,
                                                const int* __restrict__ nodeptr,
                                                const float* __restrict__ tt,
                                                const float* __restrict__ bias,
                                                const float* __restrict__ dinv,
                                                float* __restrict__ out) {
    int tid = blockIdx.x * 256 + threadIdx.x;
    int n = tid >> 2;
    int j = tid & 3;
    if (n >= NN) return;
    int e0 = nodeptr[n];
    int e1 = nodeptr[n + 1];
    float acc = 0.0f;
    for (int base = e0; base < e1; base += 4) {
        int idx = base + j;
        int key = 0; float w = 0.0f;
        if (idx < e1) { key = (int)skey[idx]; w = sval[idx]; }
        int cnt = e1 - base;
        if (cnt >= 4) {
#pragma unroll
            for (int q = 0; q < 4; q++) {
                int r = __shfl(key, q, 4);
                float ww = __shfl(w, q, 4);
                acc += ww * tt[((size_t)r << 2) + j];
            }
        } else {
            for (int q = 0; q < cnt; q++) {
                int r = __shfl(key, q, 4);
                float ww = __shfl(w, q, 4);
                acc += ww * tt[((size_t)r << 2) + j];
            }
        }
    }
    float di = dinv[n];
    float logit = bias[j] + di * (acc + tt[((size_t)n << 2) + j]);
    float m = logit;
    m = fmaxf(m, __shfl_xor(m, 1, 4));
    m = fmaxf(m, __shfl_xor(m, 2, 4));
    float ex = expf(logit - m);
    float s = ex;
    s += __shfl_xor(s, 1, 4);
    s += __shfl_xor(s, 2, 4);
    out[((size_t)n << 2) + j] = logit - m - logf(s);
}

extern "C" void kernel_launch(void* const* d_in, const int* in_sizes, int n_in,
                              void* d_out, int out_size, void* d_ws, size_t ws_size,
                              hipStream_t stream) {
    const float* x  = (const float*)d_in[0];
    const int*   ei = (const int*)d_in[1];   // [2, E]: row then col (int32 from harness)
    const float* ew = (const float*)d_in[2];
    const float* W1 = (const float*)d_in[3];
    const float* b1 = (const float*)d_in[4];
    const float* W3 = (const float*)d_in[5];
    const float* b3 = (const float*)d_in[6];
    const float* W2 = (const float*)d_in[7];
    const float* b2 = (const float*)d_in[8];
    float* out = (float*)d_out;

    const int* row = ei;
    const int* col = ei + NE;

    // workspace layout
    char* ws = (char*)d_ws;
    float*    dinv    = (float*)ws;                         // NN
    int*      nodeptr = (int*)(dinv + NN);                  // NN+1
    unsigned* skey    = (unsigned*)(nodeptr + NN + 1);      // NE
    float*    sval    = (float*)(skey + NE);                // NE
    int*      hist    = (int*)(sval + NE);                  // NB
    int*      start   = hist + NB;                          // NB+1
    int*      curs    = start + NB + 1;                     // NB
    // bin (NE uint2, 25.6 MB) dead after k_sort -> overlap with tt buffers A,B
    char*     dyn     = (char*)(curs + NB);
    uint2*    bin     = (uint2*)dyn;
    float*    A       = (float*)dyn;                        // NN*16 tt buffer
    float*    B       = A + (size_t)NN * HID;               // NN*16 h buffer

    hipMemsetAsync(hist, 0, NB * sizeof(int), stream);

    // Build fully-sorted CSR
    k_count<<<NCHUNK, 1024, 0, stream>>>(col, hist);
    k_scan<<<1, 1024, 0, stream>>>(hist, start, curs, nodeptr);
    k_bin<<<NCHUNK, 1024, 0, stream>>>(row, col, ew, curs, bin);
    k_sort<<<NB, 1024, 0, stream>>>(bin, start, skey, sval, nodeptr, dinv);

    int gN = (NN + 255) / 256;
    int gA16 = (NN * 16 + 255) / 256;   // 6250
    int gA4  = (NN * 4 + 255) / 256;    // 1563

    // Layer 1
    k_xform1<<<gN, 256, 0, stream>>>(x, W1, dinv, A);
    k_agg16<<<gA16, 256, 0, stream>>>(skey, sval, nodeptr, A, b1, dinv, B);
    // Layer 2
    k_xform<HID><<<gN, 256, 0, stream>>>(B, W3, dinv, A);
    k_agg16<<<gA16, 256, 0, stream>>>(skey, sval, nodeptr, A, b3, dinv, B);
    // Layer 3 + fused log-softmax
    k_xform<NC><<<gN, 256, 0, stream>>>(B, W2, dinv, A);
    k_agg4sm<<<gA4, 256, 0, stream>>>(skey, sval, nodeptr, A, b2, dinv, out);
}

// Round 4
// 382.932 us; speedup vs baseline: 2.6802x; 1.0210x over previous
//
#include <hip/hip_runtime.h>
#include <math.h>

#define NN 100000
#define NE 3200000
#define F_IN 64
#define HID 16
#define NC 4

#define SZB 256            // nodes per bucket
#define NB 391             // ceil(NN / SZB)
#define CH 8192            // edges per chunk in count/bin passes
#define NCH 391            // ceil(NE / CH)

// ---------- Pass A: per-bucket histogram ----------
__global__ __launch_bounds__(256) void k_count(const int* __restrict__ col,
                                               int* __restrict__ hist) {
    __shared__ int h[NB];
    for (int i = threadIdx.x; i < NB; i += 256) h[i] = 0;
    __syncthreads();
    int e0 = blockIdx.x * CH;
    int e1 = min(e0 + CH, NE);
    for (int i = e0 + threadIdx.x; i < e1; i += 256)
        atomicAdd(&h[col[i] >> 8], 1);
    __syncthreads();
    for (int i = threadIdx.x; i < NB; i += 256)
        if (h[i]) atomicAdd(&hist[i], h[i]);
}

// ---------- Pass B: exclusive scan over NB buckets ----------
__global__ __launch_bounds__(512) void k_scan(const int* __restrict__ hist,
                                              int* __restrict__ start,
                                              int* __restrict__ cursor,
                                              int* __restrict__ nodeptr) {
    __shared__ int a[512];
    int tid = threadIdx.x;
    int h0 = (tid < NB) ? hist[tid] : 0;
    a[tid] = h0;
    for (int off = 1; off < 512; off <<= 1) {
        __syncthreads();
        int v = (tid >= off) ? a[tid - off] : 0;
        __syncthreads();
        a[tid] += v;
    }
    __syncthreads();
    if (tid < NB) {
        int ex = a[tid] - h0;
        start[tid] = ex;
        cursor[tid] = ex;
    }
    if (tid == 0) { start[NB] = NE; nodeptr[NN] = NE; }
}

// ---------- Pass C: LDS-staged chunk sort by bucket, coalesced flush ----------
// bin[pos] = { (row<<8)|col_local , bits(ew) }
__global__ __launch_bounds__(256) void k_bin(const int* __restrict__ row,
                                             const int* __restrict__ col,
                                             const float* __restrict__ ew,
                                             int* __restrict__ cursor,
                                             uint2* __restrict__ bin) {
    __shared__ int h[NB];          // counts -> local scatter cursor
    __shared__ int lstart[NB + 1]; // local exclusive prefix
    __shared__ int gbase[NB];      // global reserved base per bucket
    __shared__ int ps[256];
    __shared__ uint2 stage[CH];
    int tid = threadIdx.x;
    for (int i = tid; i < NB; i += 256) h[i] = 0;
    __syncthreads();
    int e0 = blockIdx.x * CH;
    int e1 = min(e0 + CH, NE);
    int eCnt = e1 - e0;
    // phase 1: histogram
    for (int i = e0 + tid; i < e1; i += 256)
        atomicAdd(&h[col[i] >> 8], 1);
    __syncthreads();
    // phase 2: scan (2 bins per thread) + global reservation
    int b0 = 2 * tid;
    int c0 = (b0 < NB) ? h[b0] : 0;
    int c1 = (b0 + 1 < NB) ? h[b0 + 1] : 0;
    ps[tid] = c0 + c1;
    for (int off = 1; off < 256; off <<= 1) {
        __syncthreads();
        int v = (tid >= off) ? ps[tid - off] : 0;
        __syncthreads();
        ps[tid] += v;
    }
    __syncthreads();
    int ex1 = ps[tid] - c1;        // exclusive prefix of bin b0+1
    int ex0 = ex1 - c0;            // exclusive prefix of bin b0
    if (b0 < NB) {
        if (c0) gbase[b0] = atomicAdd(&cursor[b0], c0);
        lstart[b0] = ex0;
        h[b0] = ex0;               // becomes local scatter cursor
    }
    if (b0 + 1 < NB) {
        if (c1) gbase[b0 + 1] = atomicAdd(&cursor[b0 + 1], c1);
        lstart[b0 + 1] = ex1;
        h[b0 + 1] = ex1;
    }
    if (tid == 255) lstart[NB] = eCnt;
    __syncthreads();
    // phase 3: scatter into LDS stage (sorted by bucket)
    for (int i = e0 + tid; i < e1; i += 256) {
        int c = col[i];
        int b = c >> 8;
        int pos = atomicAdd(&h[b], 1);
        stage[pos] = make_uint2(((unsigned)row[i] << 8) | (unsigned)(c & 255),
                                __float_as_uint(ew[i]));
    }
    __syncthreads();
    // phase 4: coalesced flush; bucket of element i via binary search in lstart
    for (int i = tid; i < eCnt; i += 256) {
        int lo = 0, hi = NB;
        while (hi - lo > 1) {
            int mid = (lo + hi) >> 1;
            if (lstart[mid] <= i) lo = mid; else hi = mid;
        }
        bin[gbase[lo] + (i - lstart[lo])] = stage[i];
    }
}

// ---------- Pass D: within-bucket counting sort -> CSR + dinv ----------
__global__ __launch_bounds__(256) void k_sort(const uint2* __restrict__ bin,
                                              const int* __restrict__ start,
                                              uint2* __restrict__ evec,
                                              int* __restrict__ nodeptr,
                                              float* __restrict__ dinv) {
    __shared__ int cnt[SZB];
    __shared__ float wdeg[SZB];
    __shared__ int ps[SZB];
    __shared__ int curp[SZB];
    int b = blockIdx.x, tid = threadIdx.x;
    cnt[tid] = 0; wdeg[tid] = 0.0f;
    __syncthreads();
    int s = start[b], e = start[b + 1];
    for (int i = s + tid; i < e; i += 256) {
        uint2 u = bin[i];
        int cl = u.x & 255;
        atomicAdd(&cnt[cl], 1);
        atomicAdd(&wdeg[cl], __uint_as_float(u.y));
    }
    __syncthreads();
    ps[tid] = cnt[tid];
    for (int off = 1; off < 256; off <<= 1) {
        __syncthreads();
        int v = (tid >= off) ? ps[tid - off] : 0;
        __syncthreads();
        ps[tid] += v;
    }
    __syncthreads();
    int ex = ps[tid] - cnt[tid];
    curp[tid] = s + ex;
    int n = b * SZB + tid;
    if (n < NN) {
        nodeptr[n] = s + ex;
        dinv[n] = rsqrtf(1.0f + wdeg[tid]);   // deg >= 1 (self-loop)
    }
    __syncthreads();
    for (int i = s + tid; i < e; i += 256) {
        uint2 u = bin[i];
        int cl = u.x & 255;
        int pos = atomicAdd(&curp[cl], 1);
        evec[pos] = make_uint2(u.x >> 8, u.y);   // {row, ew bits}
    }
}

// ---------- Layer-1 transform: tt1 = dinv * (x @ W1) ----------
__global__ __launch_bounds__(256) void k_xform1(const float* __restrict__ x,
                                                const float* __restrict__ W,
                                                const float* __restrict__ dinv,
                                                float* __restrict__ tt) {
    __shared__ float Ws[F_IN * HID];
    for (int i = threadIdx.x; i < F_IN * HID; i += 256) Ws[i] = W[i];
    __syncthreads();
    int n = blockIdx.x * blockDim.x + threadIdx.x;
    if (n >= NN) return;
    float acc[HID];
#pragma unroll
    for (int j = 0; j < HID; j++) acc[j] = 0.0f;
    const float4* xp = (const float4*)(x + (size_t)n * F_IN);
#pragma unroll
    for (int k4 = 0; k4 < F_IN / 4; k4++) {
        float4 v = xp[k4];
        int k = k4 * 4;
#pragma unroll
        for (int j = 0; j < HID; j++) {
            acc[j] += v.x * Ws[(k + 0) * HID + j];
            acc[j] += v.y * Ws[(k + 1) * HID + j];
            acc[j] += v.z * Ws[(k + 2) * HID + j];
            acc[j] += v.w * Ws[(k + 3) * HID + j];
        }
    }
    float di = dinv[n];
#pragma unroll
    for (int j = 0; j < HID; j++) tt[(size_t)n * HID + j] = di * acc[j];
}

// ---------- Fused aggregation + relu + next-layer transform ----------
// h[n][j]  = bias[j] + dinv[n]*(sum_e w_e*tt_in[row_e][j] + tt_in[n][j])
// tt_out[n][c] = dinv[n] * sum_k relu(h[n][k]) * Wn[k][c]
template <int DN>
__global__ __launch_bounds__(256) void k_aggf(const uint2* __restrict__ evec,
                                              const int* __restrict__ nodeptr,
                                              const float* __restrict__ tt_in,
                                              const float* __restrict__ bias,
                                              const float* __restrict__ dinv,
                                              const float* __restrict__ Wn,
                                              float* __restrict__ tt_out) {
    __shared__ float Ws[HID * DN];
    for (int i = threadIdx.x; i < HID * DN; i += 256) Ws[i] = Wn[i];
    __syncthreads();
    int tid = blockIdx.x * 256 + threadIdx.x;
    int n = tid >> 4;
    int j = tid & 15;
    if (n >= NN) return;
    int e0 = nodeptr[n];
    int e1 = nodeptr[n + 1];
    float acc = 0.0f;
    for (int base = e0; base < e1; base += 16) {
        int idx = base + j;
        int key = 0; float w = 0.0f;
        if (idx < e1) { uint2 u = evec[idx]; key = (int)u.x; w = __uint_as_float(u.y); }
        int c = e1 - base;
        if (c >= 16) {
#pragma unroll
            for (int q = 0; q < 16; q++) {
                int r = __shfl(key, q, 16);
                float ww = __shfl(w, q, 16);
                acc += ww * tt_in[((size_t)r << 4) + j];
            }
        } else {
            for (int q = 0; q < c; q++) {
                int r = __shfl(key, q, 16);
                float ww = __shfl(w, q, 16);
                acc += ww * tt_in[((size_t)r << 4) + j];
            }
        }
    }
    float di = dinv[n];
    float h = bias[j] + di * (acc + tt_in[((size_t)n << 4) + j]);
    h = fmaxf(h, 0.0f);
    int c = j & (DN - 1);
    float o = 0.0f;
#pragma unroll
    for (int k = 0; k < HID; k++) {
        float hk = __shfl(h, k, 16);
        o += hk * Ws[k * DN + c];
    }
    if (DN == HID || j < DN)
        tt_out[(size_t)n * DN + c] = di * o;
}

// ---------- Final aggregation (4 feats) + fused log-softmax ----------
__global__ __launch_bounds__(256) void k_agg4sm(const uint2* __restrict__ evec,
                                                const int* __restrict__ nodeptr,
                                                const float* __restrict__ tt,
                                                const float* __restrict__ bias,
                                                const float* __restrict__ dinv,
                                                float* __restrict__ out) {
    int tid = blockIdx.x * 256 + threadIdx.x;
    int n = tid >> 2;
    int j = tid & 3;
    if (n >= NN) return;
    int e0 = nodeptr[n];
    int e1 = nodeptr[n + 1];
    float acc = 0.0f;
    for (int base = e0; base < e1; base += 4) {
        int idx = base + j;
        int key = 0; float w = 0.0f;
        if (idx < e1) { uint2 u = evec[idx]; key = (int)u.x; w = __uint_as_float(u.y); }
        int c = e1 - base;
        if (c >= 4) {
#pragma unroll
            for (int q = 0; q < 4; q++) {
                int r = __shfl(key, q, 4);
                float ww = __shfl(w, q, 4);
                acc += ww * tt[((size_t)r << 2) + j];
            }
        } else {
            for (int q = 0; q < c; q++) {
                int r = __shfl(key, q, 4);
                float ww = __shfl(w, q, 4);
                acc += ww * tt[((size_t)r << 2) + j];
            }
        }
    }
    float di = dinv[n];
    float logit = bias[j] + di * (acc + tt[((size_t)n << 2) + j]);
    float m = logit;
    m = fmaxf(m, __shfl_xor(m, 1, 4));
    m = fmaxf(m, __shfl_xor(m, 2, 4));
    float ex = expf(logit - m);
    float s = ex;
    s += __shfl_xor(s, 1, 4);
    s += __shfl_xor(s, 2, 4);
    out[((size_t)n << 2) + j] = logit - m - logf(s);
}

extern "C" void kernel_launch(void* const* d_in, const int* in_sizes, int n_in,
                              void* d_out, int out_size, void* d_ws, size_t ws_size,
                              hipStream_t stream) {
    const float* x  = (const float*)d_in[0];
    const int*   ei = (const int*)d_in[1];   // [2, E]: row then col
    const float* ew = (const float*)d_in[2];
    const float* W1 = (const float*)d_in[3];
    const float* b1 = (const float*)d_in[4];
    const float* W3 = (const float*)d_in[5];
    const float* b3 = (const float*)d_in[6];
    const float* W2 = (const float*)d_in[7];
    const float* b2 = (const float*)d_in[8];
    float* out = (float*)d_out;

    const int* row = ei;
    const int* col = ei + NE;

    // workspace layout
    char* ws = (char*)d_ws;
    float* dinv    = (float*)ws;                        // NN
    int*   nodeptr = (int*)(dinv + NN);                 // NN+1
    uint2* evec    = (uint2*)(nodeptr + NN + 1);        // NE uint2 (25.6 MB)
    int*   hist    = (int*)(evec + NE);                 // NB
    int*   start   = hist + NB;                         // NB+1
    int*   curs    = start + NB + 1;                    // NB
    // bin (NE uint2) dead after k_sort -> overlap with tt buffers
    char*  dyn     = (char*)(curs + NB);
    uint2* bin     = (uint2*)dyn;                       // NE uint2 (25.6 MB)
    float* tt1     = (float*)dyn;                       // NN*16
    float* tt2     = tt1 + (size_t)NN * HID;            // NN*16
    float* tt3     = tt2 + (size_t)NN * HID;            // NN*4

    hipMemsetAsync(hist, 0, NB * sizeof(int), stream);

    // Build fully-sorted CSR (packed {row, w} edge array)
    k_count<<<NCH, 256, 0, stream>>>(col, hist);
    k_scan<<<1, 512, 0, stream>>>(hist, start, curs, nodeptr);
    k_bin<<<NCH, 256, 0, stream>>>(row, col, ew, curs, bin);
    k_sort<<<NB, 256, 0, stream>>>(bin, start, evec, nodeptr, dinv);

    int gN = (NN + 255) / 256;          // 391
    int gA16 = (NN * 16) / 256;         // 6250, exact
    int gA4  = (NN * 4 + 255) / 256;    // 1563

    // Layer 1 transform, then fused (agg+relu+matmul) x2, then final agg+softmax
    k_xform1<<<gN, 256, 0, stream>>>(x, W1, dinv, tt1);
    k_aggf<HID><<<gA16, 256, 0, stream>>>(evec, nodeptr, tt1, b1, dinv, W3, tt2);
    k_aggf<NC><<<gA16, 256, 0, stream>>>(evec, nodeptr, tt2, b3, dinv, W2, tt3);
    k_agg4sm<<<gA4, 256, 0, stream>>>(evec, nodeptr, tt3, b2, dinv, out);
}

// Round 5
// 310.444 us; speedup vs baseline: 3.3060x; 1.2335x over previous
//
#include <hip/hip_runtime.h>
#include <math.h>

#define NN 100000
#define NE 3200000
#define F_IN 64
#define HID 16
#define NC 4

#define SZB 256            // nodes per bucket
#define NB 391             // ceil(NN / SZB)
#define CH 8192            // edges per chunk in count/bin passes
#define NCH 391            // ceil(NE / CH); last chunk = 5120 (divisible by 4)

// ---------- Pass A: per-bucket histogram (int4-vectorized) ----------
__global__ __launch_bounds__(512) void k_count(const int* __restrict__ col,
                                               int* __restrict__ hist) {
    __shared__ int h[NB];
    for (int i = threadIdx.x; i < NB; i += 512) h[i] = 0;
    __syncthreads();
    int e0 = blockIdx.x * CH;
    int e1 = min(e0 + CH, NE);
    for (int i = e0 + threadIdx.x * 4; i < e1; i += 512 * 4) {
        int4 c4 = *(const int4*)(col + i);
        atomicAdd(&h[c4.x >> 8], 1);
        atomicAdd(&h[c4.y >> 8], 1);
        atomicAdd(&h[c4.z >> 8], 1);
        atomicAdd(&h[c4.w >> 8], 1);
    }
    __syncthreads();
    for (int i = threadIdx.x; i < NB; i += 512)
        if (h[i]) atomicAdd(&hist[i], h[i]);
}

// ---------- Pass B: exclusive scan over NB buckets ----------
__global__ __launch_bounds__(512) void k_scan(const int* __restrict__ hist,
                                              int* __restrict__ start,
                                              int* __restrict__ cursor,
                                              int* __restrict__ nodeptr) {
    __shared__ int a[512];
    int tid = threadIdx.x;
    int h0 = (tid < NB) ? hist[tid] : 0;
    a[tid] = h0;
    for (int off = 1; off < 512; off <<= 1) {
        __syncthreads();
        int v = (tid >= off) ? a[tid - off] : 0;
        __syncthreads();
        a[tid] += v;
    }
    __syncthreads();
    if (tid < NB) {
        int ex = a[tid] - h0;
        start[tid] = ex;
        cursor[tid] = ex;
    }
    if (tid == 0) { start[NB] = NE; nodeptr[NN] = NE; }
}

// ---------- Pass C: LDS-staged chunk sort by bucket, coalesced flush ----------
// bin[pos] = { (row<<8)|col_local , bits(ew) }
__global__ __launch_bounds__(512) void k_bin(const int* __restrict__ row,
                                             const int* __restrict__ col,
                                             const float* __restrict__ ew,
                                             int* __restrict__ cursor,
                                             uint2* __restrict__ bin) {
    __shared__ int h[NB];          // counts -> local scatter cursor
    __shared__ int lstart[NB + 1]; // local exclusive prefix
    __shared__ int gbase[NB];      // global reserved base per bucket
    __shared__ int ps[512];
    __shared__ uint2 stage[CH];
    int tid = threadIdx.x;
    for (int i = tid; i < NB; i += 512) h[i] = 0;
    __syncthreads();
    int e0 = blockIdx.x * CH;
    int e1 = min(e0 + CH, NE);
    int eCnt = e1 - e0;
    // phase 1: histogram (vectorized)
    for (int i = e0 + tid * 4; i < e1; i += 512 * 4) {
        int4 c4 = *(const int4*)(col + i);
        atomicAdd(&h[c4.x >> 8], 1);
        atomicAdd(&h[c4.y >> 8], 1);
        atomicAdd(&h[c4.z >> 8], 1);
        atomicAdd(&h[c4.w >> 8], 1);
    }
    __syncthreads();
    // phase 2: scan (1 bin per thread) + global reservation
    int c0 = (tid < NB) ? h[tid] : 0;
    ps[tid] = c0;
    for (int off = 1; off < 512; off <<= 1) {
        __syncthreads();
        int v = (tid >= off) ? ps[tid - off] : 0;
        __syncthreads();
        ps[tid] += v;
    }
    __syncthreads();
    if (tid < NB) {
        int ex = ps[tid] - c0;
        lstart[tid] = ex;
        h[tid] = ex;               // becomes local scatter cursor
        if (c0) gbase[tid] = atomicAdd(&cursor[tid], c0);
    }
    if (tid == 0) lstart[NB] = eCnt;
    __syncthreads();
    // phase 3: scatter into LDS stage (sorted by bucket), vectorized reads
    for (int i = e0 + tid * 4; i < e1; i += 512 * 4) {
        int4 c4 = *(const int4*)(col + i);
        int4 r4 = *(const int4*)(row + i);
        float4 w4 = *(const float4*)(ew + i);
        int p;
        p = atomicAdd(&h[c4.x >> 8], 1);
        stage[p] = make_uint2(((unsigned)r4.x << 8) | (c4.x & 255), __float_as_uint(w4.x));
        p = atomicAdd(&h[c4.y >> 8], 1);
        stage[p] = make_uint2(((unsigned)r4.y << 8) | (c4.y & 255), __float_as_uint(w4.y));
        p = atomicAdd(&h[c4.z >> 8], 1);
        stage[p] = make_uint2(((unsigned)r4.z << 8) | (c4.z & 255), __float_as_uint(w4.z));
        p = atomicAdd(&h[c4.w >> 8], 1);
        stage[p] = make_uint2(((unsigned)r4.w << 8) | (c4.w & 255), __float_as_uint(w4.w));
    }
    __syncthreads();
    // phase 4: coalesced flush; bucket via binary search in lstart
    for (int i = tid; i < eCnt; i += 512) {
        int lo = 0, hi = NB;
        while (hi - lo > 1) {
            int mid = (lo + hi) >> 1;
            if (lstart[mid] <= i) lo = mid; else hi = mid;
        }
        bin[gbase[lo] + (i - lstart[lo])] = stage[i];
    }
}

// ---------- Pass D: within-bucket counting sort -> CSR + dinv ----------
__global__ __launch_bounds__(1024) void k_sort(const uint2* __restrict__ bin,
                                               const int* __restrict__ start,
                                               uint2* __restrict__ evec,
                                               int* __restrict__ nodeptr,
                                               float* __restrict__ dinv) {
    __shared__ int cnt[SZB];
    __shared__ float wdeg[SZB];
    __shared__ int ps[SZB];
    __shared__ int curp[SZB];
    int b = blockIdx.x, tid = threadIdx.x;
    if (tid < SZB) { cnt[tid] = 0; wdeg[tid] = 0.0f; }
    __syncthreads();
    int s = start[b], e = start[b + 1];
    for (int i = s + tid; i < e; i += 1024) {
        uint2 u = bin[i];
        int cl = u.x & 255;
        atomicAdd(&cnt[cl], 1);
        atomicAdd(&wdeg[cl], __uint_as_float(u.y));
    }
    __syncthreads();
    if (tid < SZB) ps[tid] = cnt[tid];
    for (int off = 1; off < SZB; off <<= 1) {
        __syncthreads();
        int v = (tid < SZB && tid >= off) ? ps[tid - off] : 0;
        __syncthreads();
        if (tid < SZB) ps[tid] += v;
    }
    __syncthreads();
    if (tid < SZB) {
        int ex = ps[tid] - cnt[tid];
        curp[tid] = s + ex;
        int n = b * SZB + tid;
        if (n < NN) {
            nodeptr[n] = s + ex;
            dinv[n] = rsqrtf(1.0f + wdeg[tid]);   // deg >= 1 (self-loop)
        }
    }
    __syncthreads();
    for (int i = s + tid; i < e; i += 1024) {
        uint2 u = bin[i];
        int cl = u.x & 255;
        int pos = atomicAdd(&curp[cl], 1);
        evec[pos] = make_uint2(u.x >> 8, u.y);   // {row, ew bits}
    }
}

// ---------- Layer-1 transform: tt1 = dinv * (x @ W1) ----------
__global__ __launch_bounds__(256) void k_xform1(const float* __restrict__ x,
                                                const float* __restrict__ W,
                                                const float* __restrict__ dinv,
                                                float* __restrict__ tt) {
    __shared__ float Ws[F_IN * HID];
    for (int i = threadIdx.x; i < F_IN * HID; i += 256) Ws[i] = W[i];
    __syncthreads();
    int n = blockIdx.x * blockDim.x + threadIdx.x;
    if (n >= NN) return;
    float acc[HID];
#pragma unroll
    for (int j = 0; j < HID; j++) acc[j] = 0.0f;
    const float4* xp = (const float4*)(x + (size_t)n * F_IN);
#pragma unroll
    for (int k4 = 0; k4 < F_IN / 4; k4++) {
        float4 v = xp[k4];
        int k = k4 * 4;
#pragma unroll
        for (int j = 0; j < HID; j++) {
            acc[j] += v.x * Ws[(k + 0) * HID + j];
            acc[j] += v.y * Ws[(k + 1) * HID + j];
            acc[j] += v.z * Ws[(k + 2) * HID + j];
            acc[j] += v.w * Ws[(k + 3) * HID + j];
        }
    }
    float di = dinv[n];
#pragma unroll
    for (int j = 0; j < HID; j++) tt[(size_t)n * HID + j] = di * acc[j];
}

// ---------- Fused aggregation + relu + next-layer transform ----------
// h[n][j]  = bias[j] + dinv[n]*(sum_e w_e*tt_in[row_e][j] + tt_in[n][j])
// tt_out[n][c] = dinv[n] * sum_k relu(h[n][k]) * Wn[k][c]
// Inactive lanes carry w=0,key=0 -> garbage gathers hit tt_in line 0 (L1-hot),
// contribute 0; no divergent tail path. Next batch's evec load is prefetched.
template <int DN>
__global__ __launch_bounds__(256) void k_aggf(const uint2* __restrict__ evec,
                                              const int* __restrict__ nodeptr,
                                              const float* __restrict__ tt_in,
                                              const float* __restrict__ bias,
                                              const float* __restrict__ dinv,
                                              const float* __restrict__ Wn,
                                              float* __restrict__ tt_out) {
    __shared__ float Ws[HID * DN];
    if (threadIdx.x < HID * DN) Ws[threadIdx.x] = Wn[threadIdx.x];
    __syncthreads();
    int tid = blockIdx.x * 256 + threadIdx.x;
    int n = tid >> 4;
    int j = tid & 15;
    if (n >= NN) return;
    int e0 = nodeptr[n];
    int e1 = nodeptr[n + 1];
    float self = tt_in[((size_t)n << 4) + j];
    float acc = 0.0f;
    int idx = e0 + j;
    uint2 u = (idx < e1) ? evec[idx] : make_uint2(0u, 0u);
    for (int base = e0; base < e1; base += 16) {
        int nidx = base + 16 + j;
        uint2 un = (nidx < e1) ? evec[nidx] : make_uint2(0u, 0u);
#pragma unroll
        for (int q = 0; q < 16; q++) {
            int r = __shfl((int)u.x, q, 16);
            float ww = __shfl(__uint_as_float(u.y), q, 16);
            acc += ww * tt_in[((size_t)r << 4) + j];
        }
        u = un;
    }
    float di = dinv[n];
    float h = fmaxf(bias[j] + di * (acc + self), 0.0f);
    int c = j & (DN - 1);
    float o = 0.0f;
#pragma unroll
    for (int k = 0; k < HID; k++) {
        float hk = __shfl(h, k, 16);
        o += hk * Ws[k * DN + c];
    }
    if (DN == HID || j < DN)
        tt_out[(size_t)n * DN + c] = di * o;
}

// ---------- Final aggregation (4 feats) + fused log-softmax ----------
__global__ __launch_bounds__(256) void k_agg4sm(const uint2* __restrict__ evec,
                                                const int* __restrict__ nodeptr,
                                                const float* __restrict__ tt,
                                                const float* __restrict__ bias,
                                                const float* __restrict__ dinv,
                                                float* __restrict__ out) {
    int tid = blockIdx.x * 256 + threadIdx.x;
    int n = tid >> 2;
    int j = tid & 3;
    if (n >= NN) return;
    int e0 = nodeptr[n];
    int e1 = nodeptr[n + 1];
    float self = tt[((size_t)n << 2) + j];
    float acc = 0.0f;
    int idx = e0 + j;
    uint2 u = (idx < e1) ? evec[idx] : make_uint2(0u, 0u);
    for (int base = e0; base < e1; base += 4) {
        int nidx = base + 4 + j;
        uint2 un = (nidx < e1) ? evec[nidx] : make_uint2(0u, 0u);
#pragma unroll
        for (int q = 0; q < 4; q++) {
            int r = __shfl((int)u.x, q, 4);
            float ww = __shfl(__uint_as_float(u.y), q, 4);
            acc += ww * tt[((size_t)r << 2) + j];
        }
        u = un;
    }
    float di = dinv[n];
    float logit = bias[j] + di * (acc + self);
    float m = logit;
    m = fmaxf(m, __shfl_xor(m, 1, 4));
    m = fmaxf(m, __shfl_xor(m, 2, 4));
    float ex = expf(logit - m);
    float s = ex;
    s += __shfl_xor(s, 1, 4);
    s += __shfl_xor(s, 2, 4);
    out[((size_t)n << 2) + j] = logit - m - logf(s);
}

extern "C" void kernel_launch(void* const* d_in, const int* in_sizes, int n_in,
                              void* d_out, int out_size, void* d_ws, size_t ws_size,
                              hipStream_t stream) {
    const float* x  = (const float*)d_in[0];
    const int*   ei = (const int*)d_in[1];   // [2, E]: row then col
    const float* ew = (const float*)d_in[2];
    const float* W1 = (const float*)d_in[3];
    const float* b1 = (const float*)d_in[4];
    const float* W3 = (const float*)d_in[5];
    const float* b3 = (const float*)d_in[6];
    const float* W2 = (const float*)d_in[7];
    const float* b2 = (const float*)d_in[8];
    float* out = (float*)d_out;

    const int* row = ei;
    const int* col = ei + NE;

    // workspace layout
    char* ws = (char*)d_ws;
    float* dinv    = (float*)ws;                        // NN
    int*   nodeptr = (int*)(dinv + NN);                 // NN+1
    uint2* evec    = (uint2*)(nodeptr + NN + 1);        // NE uint2 (25.6 MB)
    int*   hist    = (int*)(evec + NE);                 // NB
    int*   start   = hist + NB;                         // NB+1
    int*   curs    = start + NB + 1;                    // NB
    // bin (NE uint2) dead after k_sort -> overlap with tt buffers
    char*  dyn     = (char*)(curs + NB);
    uint2* bin     = (uint2*)dyn;                       // NE uint2 (25.6 MB)
    float* tt1     = (float*)dyn;                       // NN*16
    float* tt2     = tt1 + (size_t)NN * HID;            // NN*16
    float* tt3     = tt2 + (size_t)NN * HID;            // NN*4

    hipMemsetAsync(hist, 0, NB * sizeof(int), stream);

    // Build fully-sorted CSR (packed {row, w} edge array)
    k_count<<<NCH, 512, 0, stream>>>(col, hist);
    k_scan<<<1, 512, 0, stream>>>(hist, start, curs, nodeptr);
    k_bin<<<NCH, 512, 0, stream>>>(row, col, ew, curs, bin);
    k_sort<<<NB, 1024, 0, stream>>>(bin, start, evec, nodeptr, dinv);

    int gN = (NN + 255) / 256;          // 391
    int gA16 = (NN * 16) / 256;         // 6250, exact
    int gA4  = (NN * 4 + 255) / 256;    // 1563

    // Layer 1 transform, then fused (agg+relu+matmul) x2, then final agg+softmax
    k_xform1<<<gN, 256, 0, stream>>>(x, W1, dinv, tt1);
    k_aggf<HID><<<gA16, 256, 0, stream>>>(evec, nodeptr, tt1, b1, dinv, W3, tt2);
    k_aggf<NC><<<gA16, 256, 0, stream>>>(evec, nodeptr, tt2, b3, dinv, W2, tt3);
    k_agg4sm<<<gA4, 256, 0, stream>>>(evec, nodeptr, tt3, b2, dinv, out);
}

// Round 6
// 279.620 us; speedup vs baseline: 3.6704x; 1.1102x over previous
//
#include <hip/hip_runtime.h>
#include <math.h>

#define NN 100000
#define NE 3200000
#define F_IN 64
#define HID 16
#define NC 4

#define SZB 256            // nodes per bucket
#define NB 391             // ceil(NN / SZB)
#define CH 8192            // edges per chunk in count/bin passes
#define NCH 391            // ceil(NE / CH); last chunk = 5120 (divisible by 4)
#define SCAP 9216          // k_sort LDS stage capacity (mean 8184, std ~90)

typedef _Float16 half_t;

// ---------- Pass A: per-bucket histogram (int4-vectorized) ----------
__global__ __launch_bounds__(1024) void k_count(const int* __restrict__ col,
                                                int* __restrict__ hist) {
    __shared__ int h[NB];
    for (int i = threadIdx.x; i < NB; i += 1024) h[i] = 0;
    __syncthreads();
    int e0 = blockIdx.x * CH;
    int e1 = min(e0 + CH, NE);
    for (int i = e0 + threadIdx.x * 4; i < e1; i += 1024 * 4) {
        int4 c4 = *(const int4*)(col + i);
        atomicAdd(&h[c4.x >> 8], 1);
        atomicAdd(&h[c4.y >> 8], 1);
        atomicAdd(&h[c4.z >> 8], 1);
        atomicAdd(&h[c4.w >> 8], 1);
    }
    __syncthreads();
    for (int i = threadIdx.x; i < NB; i += 1024)
        if (h[i]) atomicAdd(&hist[i], h[i]);
}

// ---------- Pass B: exclusive scan over NB buckets ----------
__global__ __launch_bounds__(512) void k_scan(const int* __restrict__ hist,
                                              int* __restrict__ start,
                                              int* __restrict__ cursor,
                                              int* __restrict__ nodeptr) {
    __shared__ int a[512];
    int tid = threadIdx.x;
    int h0 = (tid < NB) ? hist[tid] : 0;
    a[tid] = h0;
    for (int off = 1; off < 512; off <<= 1) {
        __syncthreads();
        int v = (tid >= off) ? a[tid - off] : 0;
        __syncthreads();
        a[tid] += v;
    }
    __syncthreads();
    if (tid < NB) {
        int ex = a[tid] - h0;
        start[tid] = ex;
        cursor[tid] = ex;
    }
    if (tid == 0) { start[NB] = NE; nodeptr[NN] = NE; }
}

// ---------- Pass C: LDS-staged chunk sort by bucket, coalesced flush ----------
// bin[pos] = { (row<<8)|col_local , bits(ew) }
__global__ __launch_bounds__(1024) void k_bin(const int* __restrict__ row,
                                              const int* __restrict__ col,
                                              const float* __restrict__ ew,
                                              int* __restrict__ cursor,
                                              uint2* __restrict__ bin) {
    __shared__ int h[NB];          // counts -> local scatter cursor
    __shared__ int lstart[NB + 1]; // local exclusive prefix
    __shared__ int gbase[NB];      // global reserved base per bucket
    __shared__ int ps[1024];
    __shared__ uint2 stage[CH];
    int tid = threadIdx.x;
    for (int i = tid; i < NB; i += 1024) h[i] = 0;
    __syncthreads();
    int e0 = blockIdx.x * CH;
    int e1 = min(e0 + CH, NE);
    int eCnt = e1 - e0;
    // phase 1: histogram (vectorized)
    for (int i = e0 + tid * 4; i < e1; i += 1024 * 4) {
        int4 c4 = *(const int4*)(col + i);
        atomicAdd(&h[c4.x >> 8], 1);
        atomicAdd(&h[c4.y >> 8], 1);
        atomicAdd(&h[c4.z >> 8], 1);
        atomicAdd(&h[c4.w >> 8], 1);
    }
    __syncthreads();
    // phase 2: scan (1 bin per thread) + global reservation
    int c0 = (tid < NB) ? h[tid] : 0;
    ps[tid] = c0;
    for (int off = 1; off < 1024; off <<= 1) {
        __syncthreads();
        int v = (tid >= off) ? ps[tid - off] : 0;
        __syncthreads();
        ps[tid] += v;
    }
    __syncthreads();
    if (tid < NB) {
        int ex = ps[tid] - c0;
        lstart[tid] = ex;
        h[tid] = ex;               // becomes local scatter cursor
        if (c0) gbase[tid] = atomicAdd(&cursor[tid], c0);
    }
    if (tid == 0) lstart[NB] = eCnt;
    __syncthreads();
    // phase 3: scatter into LDS stage (sorted by bucket), vectorized reads
    for (int i = e0 + tid * 4; i < e1; i += 1024 * 4) {
        int4 c4 = *(const int4*)(col + i);
        int4 r4 = *(const int4*)(row + i);
        float4 w4 = *(const float4*)(ew + i);
        int p;
        p = atomicAdd(&h[c4.x >> 8], 1);
        stage[p] = make_uint2(((unsigned)r4.x << 8) | (c4.x & 255), __float_as_uint(w4.x));
        p = atomicAdd(&h[c4.y >> 8], 1);
        stage[p] = make_uint2(((unsigned)r4.y << 8) | (c4.y & 255), __float_as_uint(w4.y));
        p = atomicAdd(&h[c4.z >> 8], 1);
        stage[p] = make_uint2(((unsigned)r4.z << 8) | (c4.z & 255), __float_as_uint(w4.z));
        p = atomicAdd(&h[c4.w >> 8], 1);
        stage[p] = make_uint2(((unsigned)r4.w << 8) | (c4.w & 255), __float_as_uint(w4.w));
    }
    __syncthreads();
    // phase 4: coalesced flush; bucket via binary search in lstart (ILP x2 unroll)
    for (int i = tid; i < eCnt; i += 1024) {
        int lo = 0, hi = NB;
#pragma unroll 3
        while (hi - lo > 1) {
            int mid = (lo + hi) >> 1;
            if (lstart[mid] <= i) lo = mid; else hi = mid;
        }
        bin[gbase[lo] + (i - lstart[lo])] = stage[i];
    }
}

// ---------- Pass D: within-bucket counting sort (LDS-staged) -> CSR + dinv ----------
__global__ __launch_bounds__(1024) void k_sort(const uint2* __restrict__ bin,
                                               const int* __restrict__ start,
                                               uint2* __restrict__ evec,
                                               int* __restrict__ nodeptr,
                                               float* __restrict__ dinv) {
    __shared__ int cnt[SZB];
    __shared__ float wdeg[SZB];
    __shared__ int ps[SZB];
    __shared__ int curp[SZB];
    __shared__ uint2 stage[SCAP];
    int b = blockIdx.x, tid = threadIdx.x;
    if (tid < SZB) { cnt[tid] = 0; wdeg[tid] = 0.0f; }
    __syncthreads();
    int s = start[b], e = start[b + 1];
    int m = e - s;
    for (int i = s + tid; i < e; i += 1024) {
        uint2 u = bin[i];
        int cl = u.x & 255;
        atomicAdd(&cnt[cl], 1);
        atomicAdd(&wdeg[cl], __uint_as_float(u.y));
    }
    __syncthreads();
    if (tid < SZB) ps[tid] = cnt[tid];
    for (int off = 1; off < SZB; off <<= 1) {
        __syncthreads();
        int v = (tid < SZB && tid >= off) ? ps[tid - off] : 0;
        __syncthreads();
        if (tid < SZB) ps[tid] += v;
    }
    __syncthreads();
    if (tid < SZB) {
        int ex = ps[tid] - cnt[tid];
        int n = b * SZB + tid;
        if (n < NN) {
            nodeptr[n] = s + ex;
            dinv[n] = rsqrtf(1.0f + wdeg[tid]);   // deg >= 1 (self-loop)
        }
        curp[tid] = (m <= SCAP) ? ex : (s + ex);  // local vs global cursor
    }
    __syncthreads();
    if (m <= SCAP) {
        // scatter into LDS stage, then coalesced flush
        for (int i = s + tid; i < e; i += 1024) {
            uint2 u = bin[i];
            int cl = u.x & 255;
            int pos = atomicAdd(&curp[cl], 1);
            stage[pos] = make_uint2(u.x >> 8, u.y);   // {row, ew bits}
        }
        __syncthreads();
        for (int i = tid; i < m; i += 1024)
            evec[s + i] = stage[i];
    } else {
        // fallback: direct global scatter (never expected for this dataset)
        for (int i = s + tid; i < e; i += 1024) {
            uint2 u = bin[i];
            int cl = u.x & 255;
            int pos = atomicAdd(&curp[cl], 1);
            evec[pos] = make_uint2(u.x >> 8, u.y);
        }
    }
}

// ---------- Layer-1 transform: tt1 = fp16( dinv * (x @ W1) ) ----------
__global__ __launch_bounds__(256) void k_xform1(const float* __restrict__ x,
                                                const float* __restrict__ W,
                                                const float* __restrict__ dinv,
                                                half_t* __restrict__ tt) {
    __shared__ float Ws[F_IN * HID];
    for (int i = threadIdx.x; i < F_IN * HID; i += 256) Ws[i] = W[i];
    __syncthreads();
    int n = blockIdx.x * blockDim.x + threadIdx.x;
    if (n >= NN) return;
    float acc[HID];
#pragma unroll
    for (int j = 0; j < HID; j++) acc[j] = 0.0f;
    const float4* xp = (const float4*)(x + (size_t)n * F_IN);
#pragma unroll
    for (int k4 = 0; k4 < F_IN / 4; k4++) {
        float4 v = xp[k4];
        int k = k4 * 4;
#pragma unroll
        for (int j = 0; j < HID; j++) {
            acc[j] += v.x * Ws[(k + 0) * HID + j];
            acc[j] += v.y * Ws[(k + 1) * HID + j];
            acc[j] += v.z * Ws[(k + 2) * HID + j];
            acc[j] += v.w * Ws[(k + 3) * HID + j];
        }
    }
    float di = dinv[n];
#pragma unroll
    for (int j = 0; j < HID; j++) tt[(size_t)n * HID + j] = (half_t)(di * acc[j]);
}

// ---------- Fused aggregation + relu + next-layer transform (fp16 tt) ----------
// h[n][j]  = bias[j] + dinv[n]*(sum_e w_e*tt_in[row_e][j] + tt_in[n][j])
// tt_out[n][c] = dinv[n] * sum_k relu(h[n][k]) * Wn[k][c]
template <int DN>
__global__ __launch_bounds__(256) void k_aggf(const uint2* __restrict__ evec,
                                              const int* __restrict__ nodeptr,
                                              const half_t* __restrict__ tt_in,
                                              const float* __restrict__ bias,
                                              const float* __restrict__ dinv,
                                              const float* __restrict__ Wn,
                                              half_t* __restrict__ tt_out) {
    __shared__ float Ws[HID * DN];
    if (threadIdx.x < HID * DN) Ws[threadIdx.x] = Wn[threadIdx.x];
    __syncthreads();
    int tid = blockIdx.x * 256 + threadIdx.x;
    int n = tid >> 4;
    int j = tid & 15;
    if (n >= NN) return;
    int e0 = nodeptr[n];
    int e1 = nodeptr[n + 1];
    float self = (float)tt_in[((size_t)n << 4) + j];
    float acc = 0.0f;
    int idx = e0 + j;
    uint2 u = (idx < e1) ? evec[idx] : make_uint2(0u, 0u);
    for (int base = e0; base < e1; base += 16) {
        int nidx = base + 16 + j;
        uint2 un = (nidx < e1) ? evec[nidx] : make_uint2(0u, 0u);
#pragma unroll
        for (int q = 0; q < 16; q++) {
            int r = __shfl((int)u.x, q, 16);
            float ww = __shfl(__uint_as_float(u.y), q, 16);
            acc += ww * (float)tt_in[((size_t)r << 4) + j];
        }
        u = un;
    }
    float di = dinv[n];
    float h = fmaxf(bias[j] + di * (acc + self), 0.0f);
    int c = j & (DN - 1);
    float o = 0.0f;
#pragma unroll
    for (int k = 0; k < HID; k++) {
        float hk = __shfl(h, k, 16);
        o += hk * Ws[k * DN + c];
    }
    if (DN == HID || j < DN)
        tt_out[(size_t)n * DN + c] = (half_t)(di * o);
}

// ---------- Final aggregation (4 feats) + fused log-softmax ----------
__global__ __launch_bounds__(256) void k_agg4sm(const uint2* __restrict__ evec,
                                                const int* __restrict__ nodeptr,
                                                const half_t* __restrict__ tt,
                                                const float* __restrict__ bias,
                                                const float* __restrict__ dinv,
                                                float* __restrict__ out) {
    int tid = blockIdx.x * 256 + threadIdx.x;
    int n = tid >> 2;
    int j = tid & 3;
    if (n >= NN) return;
    int e0 = nodeptr[n];
    int e1 = nodeptr[n + 1];
    float self = (float)tt[((size_t)n << 2) + j];
    float acc = 0.0f;
    int idx = e0 + j;
    uint2 u = (idx < e1) ? evec[idx] : make_uint2(0u, 0u);
    for (int base = e0; base < e1; base += 4) {
        int nidx = base + 4 + j;
        uint2 un = (nidx < e1) ? evec[nidx] : make_uint2(0u, 0u);
#pragma unroll
        for (int q = 0; q < 4; q++) {
            int r = __shfl((int)u.x, q, 4);
            float ww = __shfl(__uint_as_float(u.y), q, 4);
            acc += ww * (float)tt[((size_t)r << 2) + j];
        }
        u = un;
    }
    float di = dinv[n];
    float logit = bias[j] + di * (acc + self);
    float m = logit;
    m = fmaxf(m, __shfl_xor(m, 1, 4));
    m = fmaxf(m, __shfl_xor(m, 2, 4));
    float ex = expf(logit - m);
    float s = ex;
    s += __shfl_xor(s, 1, 4);
    s += __shfl_xor(s, 2, 4);
    out[((size_t)n << 2) + j] = logit - m - logf(s);
}

extern "C" void kernel_launch(void* const* d_in, const int* in_sizes, int n_in,
                              void* d_out, int out_size, void* d_ws, size_t ws_size,
                              hipStream_t stream) {
    const float* x  = (const float*)d_in[0];
    const int*   ei = (const int*)d_in[1];   // [2, E]: row then col
    const float* ew = (const float*)d_in[2];
    const float* W1 = (const float*)d_in[3];
    const float* b1 = (const float*)d_in[4];
    const float* W3 = (const float*)d_in[5];
    const float* b3 = (const float*)d_in[6];
    const float* W2 = (const float*)d_in[7];
    const float* b2 = (const float*)d_in[8];
    float* out = (float*)d_out;

    const int* row = ei;
    const int* col = ei + NE;

    // workspace layout
    char* ws = (char*)d_ws;
    float* dinv    = (float*)ws;                        // NN
    int*   nodeptr = (int*)(dinv + NN);                 // NN+1
    uint2* evec    = (uint2*)(nodeptr + NN + 1);        // NE uint2 (25.6 MB)
    int*   hist    = (int*)(evec + NE);                 // NB
    int*   start   = hist + NB;                         // NB+1
    int*   curs    = start + NB + 1;                    // NB
    // bin (NE uint2) dead after k_sort -> overlap with tt buffers
    char*  dyn     = (char*)(curs + NB);
    uint2* bin     = (uint2*)dyn;                       // NE uint2 (25.6 MB)
    half_t* tt1    = (half_t*)dyn;                      // NN*16 fp16 (3.2 MB)
    half_t* tt2    = tt1 + (size_t)NN * HID;            // NN*16 fp16
    half_t* tt3    = tt2 + (size_t)NN * HID;            // NN*4 fp16

    hipMemsetAsync(hist, 0, NB * sizeof(int), stream);

    // Build fully-sorted CSR (packed {row, w} edge array)
    k_count<<<NCH, 1024, 0, stream>>>(col, hist);
    k_scan<<<1, 512, 0, stream>>>(hist, start, curs, nodeptr);
    k_bin<<<NCH, 1024, 0, stream>>>(row, col, ew, curs, bin);
    k_sort<<<NB, 1024, 0, stream>>>(bin, start, evec, nodeptr, dinv);

    int gN = (NN + 255) / 256;          // 391
    int gA16 = (NN * 16) / 256;         // 6250, exact
    int gA4  = (NN * 4 + 255) / 256;    // 1563

    // Layer 1 transform, then fused (agg+relu+matmul) x2, then final agg+softmax
    k_xform1<<<gN, 256, 0, stream>>>(x, W1, dinv, tt1);
    k_aggf<HID><<<gA16, 256, 0, stream>>>(evec, nodeptr, tt1, b1, dinv, W3, tt2);
    k_aggf<NC><<<gA16, 256, 0, stream>>>(evec, nodeptr, tt2, b3, dinv, W2, tt3);
    k_agg4sm<<<gA4, 256, 0, stream>>>(evec, nodeptr, tt3, b2, dinv, out);
}

// Round 7
// 279.328 us; speedup vs baseline: 3.6742x; 1.0010x over previous
//
#include <hip/hip_runtime.h>
#include <math.h>

#define NN 100000
#define NE 3200000
#define F_IN 64
#define HID 16
#define NC 4

#define SZB 128            // nodes per bucket
#define NB 782             // ceil(NN / SZB)
#define CAP 5120           // bucket edge capacity (mean 4092, sigma ~64 -> 16 sigma)
#define CH 4096            // edges per chunk in bin pass
#define NCH 782            // ceil(NE / CH); last chunk = 1024 (divisible by 4)

typedef _Float16 half_t;
typedef _Float16 h4f __attribute__((ext_vector_type(4)));

// ---------- init per-bucket cursors ----------
__global__ __launch_bounds__(1024) void k_initcur(int* __restrict__ cursor) {
    int i = threadIdx.x;
    if (i < NB) cursor[i] = i * CAP;
}

// ---------- Pass A: LDS-staged chunk sort by bucket, coalesced flush ----------
// bkey[pos] = (row<<7)|col_local ; bw[pos] = fp16(ew)
__global__ __launch_bounds__(512) void k_bin(const int* __restrict__ row,
                                             const int* __restrict__ col,
                                             const float* __restrict__ ew,
                                             int* __restrict__ cursor,
                                             unsigned* __restrict__ bkey,
                                             half_t* __restrict__ bw) {
    __shared__ int h[NB];          // counts -> local scatter cursor
    __shared__ int lstart[NB + 1]; // local exclusive prefix
    __shared__ int gbase[NB];      // global reserved base per bucket
    __shared__ int ps[512];
    __shared__ unsigned skey_st[CH];
    __shared__ half_t sw_st[CH];
    int tid = threadIdx.x;
    for (int i = tid; i < NB; i += 512) h[i] = 0;
    __syncthreads();
    int e0 = blockIdx.x * CH;
    int e1 = min(e0 + CH, NE);
    int eCnt = e1 - e0;
    // phase 1: histogram (vectorized)
    for (int i = e0 + tid * 4; i < e1; i += 512 * 4) {
        int4 c4 = *(const int4*)(col + i);
        atomicAdd(&h[c4.x >> 7], 1);
        atomicAdd(&h[c4.y >> 7], 1);
        atomicAdd(&h[c4.z >> 7], 1);
        atomicAdd(&h[c4.w >> 7], 1);
    }
    __syncthreads();
    // phase 2: pair-scan over NB bins + global reservation
    int b0 = 2 * tid;
    int c0 = (b0 < NB) ? h[b0] : 0;
    int c1 = (b0 + 1 < NB) ? h[b0 + 1] : 0;
    ps[tid] = c0 + c1;
    for (int off = 1; off < 512; off <<= 1) {
        __syncthreads();
        int v = (tid >= off) ? ps[tid - off] : 0;
        __syncthreads();
        ps[tid] += v;
    }
    __syncthreads();
    int ex1 = ps[tid] - c1;
    int ex0 = ex1 - c0;
    if (b0 < NB) {
        lstart[b0] = ex0;
        h[b0] = ex0;
        if (c0) gbase[b0] = atomicAdd(&cursor[b0], c0);
    }
    if (b0 + 1 < NB) {
        lstart[b0 + 1] = ex1;
        h[b0 + 1] = ex1;
        if (c1) gbase[b0 + 1] = atomicAdd(&cursor[b0 + 1], c1);
    }
    if (tid == 0) lstart[NB] = eCnt;
    __syncthreads();
    // phase 3: scatter into LDS stage (sorted by bucket)
    for (int i = e0 + tid * 4; i < e1; i += 512 * 4) {
        int4 c4 = *(const int4*)(col + i);
        int4 r4 = *(const int4*)(row + i);
        float4 w4 = *(const float4*)(ew + i);
        int p;
        p = atomicAdd(&h[c4.x >> 7], 1);
        skey_st[p] = ((unsigned)r4.x << 7) | (c4.x & 127); sw_st[p] = (half_t)w4.x;
        p = atomicAdd(&h[c4.y >> 7], 1);
        skey_st[p] = ((unsigned)r4.y << 7) | (c4.y & 127); sw_st[p] = (half_t)w4.y;
        p = atomicAdd(&h[c4.z >> 7], 1);
        skey_st[p] = ((unsigned)r4.z << 7) | (c4.z & 127); sw_st[p] = (half_t)w4.z;
        p = atomicAdd(&h[c4.w >> 7], 1);
        skey_st[p] = ((unsigned)r4.w << 7) | (c4.w & 127); sw_st[p] = (half_t)w4.w;
    }
    __syncthreads();
    // phase 4: coalesced flush; bucket via binary search in lstart
    for (int i = tid; i < eCnt; i += 512) {
        int lo = 0, hi = NB;
        while (hi - lo > 1) {
            int mid = (lo + hi) >> 1;
            if (lstart[mid] <= i) lo = mid; else hi = mid;
        }
        int d = gbase[lo] + (i - lstart[lo]);
        bkey[d] = skey_st[i];
        bw[d] = sw_st[i];
    }
}

// ---------- Pass B: within-bucket counting sort -> node-sorted SoA + CSR + dinv ----------
__global__ __launch_bounds__(512) void k_sort(const unsigned* __restrict__ bkey,
                                              const half_t* __restrict__ bw,
                                              const int* __restrict__ cursor,
                                              unsigned* __restrict__ ekey,
                                              half_t* __restrict__ ew16,
                                              int2* __restrict__ nodeptr2,
                                              float* __restrict__ dinv) {
    __shared__ int cnt[SZB];
    __shared__ float wdeg[SZB];
    __shared__ int ps[SZB];
    __shared__ int curp[SZB];
    __shared__ unsigned skey_st[CAP];
    __shared__ half_t sw_st[CAP];
    int b = blockIdx.x, tid = threadIdx.x;
    if (tid < SZB) { cnt[tid] = 0; wdeg[tid] = 0.0f; }
    __syncthreads();
    int s = b * CAP, e = cursor[b];
    int m = e - s;
    for (int i = s + tid; i < e; i += 512) {
        unsigned k = bkey[i];
        float w = (float)bw[i];
        int cl = k & 127;
        atomicAdd(&cnt[cl], 1);
        atomicAdd(&wdeg[cl], w);
    }
    __syncthreads();
    if (tid < SZB) ps[tid] = cnt[tid];
    for (int off = 1; off < SZB; off <<= 1) {
        __syncthreads();
        int v = (tid < SZB && tid >= off) ? ps[tid - off] : 0;
        __syncthreads();
        if (tid < SZB) ps[tid] += v;
    }
    __syncthreads();
    if (tid < SZB) {
        int ex = ps[tid] - cnt[tid];
        curp[tid] = ex;
        int n = b * SZB + tid;
        if (n < NN) {
            nodeptr2[n] = make_int2(s + ex, s + ex + cnt[tid]);
            dinv[n] = rsqrtf(1.0f + wdeg[tid]);   // deg >= 1 (self-loop)
        }
    }
    __syncthreads();
    for (int i = s + tid; i < e; i += 512) {
        unsigned k = bkey[i];
        half_t w = bw[i];
        int cl = k & 127;
        int pos = atomicAdd(&curp[cl], 1);
        skey_st[pos] = k >> 7;
        sw_st[pos] = w;
    }
    __syncthreads();
    for (int i = tid; i < m; i += 512) {
        ekey[s + i] = skey_st[i];
        ew16[s + i] = sw_st[i];
    }
}

// ---------- Layer-1 transform: tt1 = fp16( dinv * (x @ W1) ) ----------
__global__ __launch_bounds__(256) void k_xform1(const float* __restrict__ x,
                                                const float* __restrict__ W,
                                                const float* __restrict__ dinv,
                                                half_t* __restrict__ tt) {
    __shared__ float Ws[F_IN * HID];
    for (int i = threadIdx.x; i < F_IN * HID; i += 256) Ws[i] = W[i];
    __syncthreads();
    int n = blockIdx.x * blockDim.x + threadIdx.x;
    if (n >= NN) return;
    float acc[HID];
#pragma unroll
    for (int j = 0; j < HID; j++) acc[j] = 0.0f;
    const float4* xp = (const float4*)(x + (size_t)n * F_IN);
#pragma unroll
    for (int k4 = 0; k4 < F_IN / 4; k4++) {
        float4 v = xp[k4];
        int k = k4 * 4;
#pragma unroll
        for (int j = 0; j < HID; j++) {
            acc[j] += v.x * Ws[(k + 0) * HID + j];
            acc[j] += v.y * Ws[(k + 1) * HID + j];
            acc[j] += v.z * Ws[(k + 2) * HID + j];
            acc[j] += v.w * Ws[(k + 3) * HID + j];
        }
    }
    float di = dinv[n];
    h4f* op = (h4f*)(tt + (size_t)n * HID);
#pragma unroll
    for (int g = 0; g < 4; g++) {
        h4f o;
        o.x = (half_t)(di * acc[g * 4 + 0]);
        o.y = (half_t)(di * acc[g * 4 + 1]);
        o.z = (half_t)(di * acc[g * 4 + 2]);
        o.w = (half_t)(di * acc[g * 4 + 3]);
        op[g] = o;
    }
}

// ---------- Fused aggregation + relu + next-layer transform ----------
// 4 lanes per node, 4 feats per lane; shuffle-free edge loop:
// every lane loads the 4-edge batch (group-uniform -> L1 broadcast) and
// gathers tt rows as 8B half4. Masked slots clamp key->0, w->0 (padding is
// poisoned, must not index with it).
template <int DN>
__global__ __launch_bounds__(256) void k_aggf(const unsigned* __restrict__ ekey,
                                              const half_t* __restrict__ ew16,
                                              const int2* __restrict__ nptr,
                                              const half_t* __restrict__ tt_in,
                                              const float* __restrict__ bias,
                                              const float* __restrict__ dinv,
                                              const float* __restrict__ Wn,
                                              half_t* __restrict__ tt_out) {
    __shared__ float Ws[HID * DN];
    if (threadIdx.x < HID * DN) Ws[threadIdx.x] = Wn[threadIdx.x];
    __syncthreads();
    int tid = blockIdx.x * 256 + threadIdx.x;
    int n = tid >> 2;
    int l = tid & 3;
    if (n >= NN) return;
    int2 p = nptr[n];
    const h4f* ttp = (const h4f*)tt_in;
    h4f sv = ttp[n * 4 + l];
    float ax = 0.f, ay = 0.f, az = 0.f, aw = 0.f;
    int abase = p.x & ~3;
    for (int base = abase; base < p.y; base += 4) {
        int4 k4 = *(const int4*)(ekey + base);
        h4f w4 = *(const h4f*)(ew16 + base);
        bool ok0 = (base + 0 >= p.x) & (base + 0 < p.y);
        bool ok1 = (base + 1 >= p.x) & (base + 1 < p.y);
        bool ok2 = (base + 2 >= p.x) & (base + 2 < p.y);
        bool ok3 = (base + 3 >= p.x) & (base + 3 < p.y);
        float w0 = ok0 ? (float)w4.x : 0.f; int r0 = ok0 ? k4.x : 0;
        float w1 = ok1 ? (float)w4.y : 0.f; int r1 = ok1 ? k4.y : 0;
        float w2 = ok2 ? (float)w4.z : 0.f; int r2 = ok2 ? k4.z : 0;
        float w3 = ok3 ? (float)w4.w : 0.f; int r3 = ok3 ? k4.w : 0;
        h4f v0 = ttp[r0 * 4 + l];
        h4f v1 = ttp[r1 * 4 + l];
        h4f v2 = ttp[r2 * 4 + l];
        h4f v3 = ttp[r3 * 4 + l];
        ax += w0 * (float)v0.x; ay += w0 * (float)v0.y; az += w0 * (float)v0.z; aw += w0 * (float)v0.w;
        ax += w1 * (float)v1.x; ay += w1 * (float)v1.y; az += w1 * (float)v1.z; aw += w1 * (float)v1.w;
        ax += w2 * (float)v2.x; ay += w2 * (float)v2.y; az += w2 * (float)v2.z; aw += w2 * (float)v2.w;
        ax += w3 * (float)v3.x; ay += w3 * (float)v3.y; az += w3 * (float)v3.z; aw += w3 * (float)v3.w;
    }
    float di = dinv[n];
    const float4* b4p = (const float4*)bias;
    float4 b4 = b4p[l];
    float hreg[4];
    hreg[0] = fmaxf(b4.x + di * (ax + (float)sv.x), 0.f);
    hreg[1] = fmaxf(b4.y + di * (ay + (float)sv.y), 0.f);
    hreg[2] = fmaxf(b4.z + di * (az + (float)sv.z), 0.f);
    hreg[3] = fmaxf(b4.w + di * (aw + (float)sv.w), 0.f);
    if (DN == 16) {
        float ox = 0.f, oy = 0.f, oz = 0.f, ow = 0.f;
#pragma unroll
        for (int k = 0; k < HID; k++) {
            float hk = __shfl(hreg[k & 3], k >> 2, 4);
            const float4 wk = *(const float4*)&Ws[k * 16 + 4 * l];
            ox += hk * wk.x; oy += hk * wk.y; oz += hk * wk.z; ow += hk * wk.w;
        }
        h4f ov;
        ov.x = (half_t)(di * ox); ov.y = (half_t)(di * oy);
        ov.z = (half_t)(di * oz); ov.w = (half_t)(di * ow);
        ((h4f*)tt_out)[n * 4 + l] = ov;
    } else {
        float o = 0.f;
#pragma unroll
        for (int k = 0; k < HID; k++) {
            float hk = __shfl(hreg[k & 3], k >> 2, 4);
            o += hk * Ws[k * DN + l];
        }
        tt_out[(size_t)n * DN + l] = (half_t)(di * o);
    }
}

// ---------- Final aggregation (4 feats) + fused log-softmax ----------
__global__ __launch_bounds__(256) void k_agg4sm(const unsigned* __restrict__ ekey,
                                                const half_t* __restrict__ ew16,
                                                const int2* __restrict__ nptr,
                                                const half_t* __restrict__ tt,
                                                const float* __restrict__ bias,
                                                const float* __restrict__ dinv,
                                                float* __restrict__ out) {
    int tid = blockIdx.x * 256 + threadIdx.x;
    int n = tid >> 2;
    int l = tid & 3;
    if (n >= NN) return;
    int2 p = nptr[n];
    float self = (float)tt[n * 4 + l];
    float acc = 0.f;
    int abase = p.x & ~3;
    for (int base = abase; base < p.y; base += 4) {
        int4 k4 = *(const int4*)(ekey + base);
        h4f w4 = *(const h4f*)(ew16 + base);
        bool ok0 = (base + 0 >= p.x) & (base + 0 < p.y);
        bool ok1 = (base + 1 >= p.x) & (base + 1 < p.y);
        bool ok2 = (base + 2 >= p.x) & (base + 2 < p.y);
        bool ok3 = (base + 3 >= p.x) & (base + 3 < p.y);
        float w0 = ok0 ? (float)w4.x : 0.f; int r0 = ok0 ? k4.x : 0;
        float w1 = ok1 ? (float)w4.y : 0.f; int r1 = ok1 ? k4.y : 0;
        float w2 = ok2 ? (float)w4.z : 0.f; int r2 = ok2 ? k4.z : 0;
        float w3 = ok3 ? (float)w4.w : 0.f; int r3 = ok3 ? k4.w : 0;
        acc += w0 * (float)tt[r0 * 4 + l];
        acc += w1 * (float)tt[r1 * 4 + l];
        acc += w2 * (float)tt[r2 * 4 + l];
        acc += w3 * (float)tt[r3 * 4 + l];
    }
    float di = dinv[n];
    float logit = bias[l] + di * (acc + self);
    float m = logit;
    m = fmaxf(m, __shfl_xor(m, 1, 4));
    m = fmaxf(m, __shfl_xor(m, 2, 4));
    float ex = expf(logit - m);
    float s = ex;
    s += __shfl_xor(s, 1, 4);
    s += __shfl_xor(s, 2, 4);
    out[n * 4 + l] = logit - m - logf(s);
}

extern "C" void kernel_launch(void* const* d_in, const int* in_sizes, int n_in,
                              void* d_out, int out_size, void* d_ws, size_t ws_size,
                              hipStream_t stream) {
    const float* x  = (const float*)d_in[0];
    const int*   ei = (const int*)d_in[1];   // [2, E]: row then col
    const float* ew = (const float*)d_in[2];
    const float* W1 = (const float*)d_in[3];
    const float* b1 = (const float*)d_in[4];
    const float* W3 = (const float*)d_in[5];
    const float* b3 = (const float*)d_in[6];
    const float* W2 = (const float*)d_in[7];
    const float* b2 = (const float*)d_in[8];
    float* out = (float*)d_out;

    const int* row = ei;
    const int* col = ei + NE;

    const size_t NEP = (size_t)NB * CAP;   // padded edge count
    // workspace layout (16B-aligned segments)
    char* ws = (char*)d_ws;
    size_t off = 0;
    float*    dinv     = (float*)(ws + off);    off += 400000;           // NN f32
    int2*     nodeptr2 = (int2*)(ws + off);     off += 800000;           // NN int2
    int*      cursor   = (int*)(ws + off);      off += 3136;             // NB ints
    unsigned* ekey     = (unsigned*)(ws + off); off += NEP * 4;          // 16.0 MB
    half_t*   ew16     = (half_t*)(ws + off);   off += NEP * 2;          // 8.0 MB
    unsigned* bkey     = (unsigned*)(ws + off); off += NEP * 4;          // 16.0 MB
    half_t*   bw       = (half_t*)(ws + off);   off += NEP * 2;          // 8.0 MB
    half_t*   tt1      = (half_t*)(ws + off);   off += (size_t)NN * HID * 2;
    half_t*   tt2      = (half_t*)(ws + off);   off += (size_t)NN * HID * 2;
    half_t*   tt3      = (half_t*)(ws + off);   off += (size_t)NN * NC * 2;

    // Build node-sorted SoA edge structure (two bucket passes, no global hist)
    k_initcur<<<1, 1024, 0, stream>>>(cursor);
    k_bin<<<NCH, 512, 0, stream>>>(row, col, ew, cursor, bkey, bw);
    k_sort<<<NB, 512, 0, stream>>>(bkey, bw, cursor, ekey, ew16, nodeptr2, dinv);

    int gN = (NN + 255) / 256;           // 391
    int gA = (NN * 4 + 255) / 256;       // 1563

    // Layer 1 transform, fused (agg+relu+matmul) x2, final agg+softmax
    k_xform1<<<gN, 256, 0, stream>>>(x, W1, dinv, tt1);
    k_aggf<HID><<<gA, 256, 0, stream>>>(ekey, ew16, nodeptr2, tt1, b1, dinv, W3, tt2);
    k_aggf<NC><<<gA, 256, 0, stream>>>(ekey, ew16, nodeptr2, tt2, b3, dinv, W2, tt3);
    k_agg4sm<<<gA, 256, 0, stream>>>(ekey, ew16, nodeptr2, tt3, b2, dinv, out);
}

// Round 8
// 255.096 us; speedup vs baseline: 4.0233x; 1.0950x over previous
//
#include <hip/hip_runtime.h>
#include <math.h>

#define NN 100000
#define NE 3200000
#define F_IN 64
#define HID 16
#define NC 4

#define SZB 512            // nodes per bucket
#define NB 196             // ceil(NN / SZB)
#define CAP 17920          // bucket edge capacity (mean 16327, sigma ~127 -> +12.5 sigma)
#define CH 8192            // edges per chunk in bin pass (runs of ~42/bucket)
#define NCH 391            // ceil(NE / CH); last chunk = 5120 (divisible by 4)

typedef _Float16 half_t;
typedef _Float16 h4f __attribute__((ext_vector_type(4)));

// ---------- init per-bucket cursors ----------
__global__ __launch_bounds__(256) void k_initcur(int* __restrict__ cursor) {
    int i = threadIdx.x;
    if (i < NB) cursor[i] = i * CAP;
}

// ---------- Pass A: LDS-staged chunk sort into coarse buckets ----------
// bin[pos] = { (row<<9)|col_local , f32 bits(ew) }
__global__ __launch_bounds__(1024) void k_bin(const int* __restrict__ row,
                                              const int* __restrict__ col,
                                              const float* __restrict__ ew,
                                              int* __restrict__ cursor,
                                              uint2* __restrict__ bin) {
    __shared__ int h[NB];          // counts -> local scatter cursor
    __shared__ int lstart[NB + 1]; // local exclusive prefix
    __shared__ int gbase[NB];      // global reserved base per bucket
    __shared__ int ps[256];
    __shared__ uint2 stage[CH];    // 64 KB
    int tid = threadIdx.x;
    for (int i = tid; i < NB; i += 1024) h[i] = 0;
    __syncthreads();
    int e0 = blockIdx.x * CH;
    int e1 = min(e0 + CH, NE);
    int eCnt = e1 - e0;
    // phase 1: histogram (vectorized)
    for (int i = e0 + tid * 4; i < e1; i += 1024 * 4) {
        int4 c4 = *(const int4*)(col + i);
        atomicAdd(&h[c4.x >> 9], 1);
        atomicAdd(&h[c4.y >> 9], 1);
        atomicAdd(&h[c4.z >> 9], 1);
        atomicAdd(&h[c4.w >> 9], 1);
    }
    __syncthreads();
    // phase 2: scan over NB bins (first 256 threads) + global reservation
    int c0 = (tid < NB) ? h[tid] : 0;
    if (tid < 256) ps[tid] = c0;
    for (int off = 1; off < 256; off <<= 1) {
        __syncthreads();
        int v = (tid < 256 && tid >= off) ? ps[tid - off] : 0;
        __syncthreads();
        if (tid < 256) ps[tid] += v;
    }
    __syncthreads();
    if (tid < NB) {
        int ex = ps[tid] - c0;
        lstart[tid] = ex;
        h[tid] = ex;               // becomes local scatter cursor
        if (c0) gbase[tid] = atomicAdd(&cursor[tid], c0);
    }
    if (tid == 0) lstart[NB] = eCnt;
    __syncthreads();
    // phase 3: scatter into LDS stage (sorted by bucket)
    for (int i = e0 + tid * 4; i < e1; i += 1024 * 4) {
        int4 c4 = *(const int4*)(col + i);
        int4 r4 = *(const int4*)(row + i);
        float4 w4 = *(const float4*)(ew + i);
        int p;
        p = atomicAdd(&h[c4.x >> 9], 1);
        stage[p] = make_uint2(((unsigned)r4.x << 9) | (c4.x & 511), __float_as_uint(w4.x));
        p = atomicAdd(&h[c4.y >> 9], 1);
        stage[p] = make_uint2(((unsigned)r4.y << 9) | (c4.y & 511), __float_as_uint(w4.y));
        p = atomicAdd(&h[c4.z >> 9], 1);
        stage[p] = make_uint2(((unsigned)r4.z << 9) | (c4.z & 511), __float_as_uint(w4.z));
        p = atomicAdd(&h[c4.w >> 9], 1);
        stage[p] = make_uint2(((unsigned)r4.w << 9) | (c4.w & 511), __float_as_uint(w4.w));
    }
    __syncthreads();
    // phase 4: coalesced flush; bucket via binary search in lstart (~8 steps)
    for (int i = tid; i < eCnt; i += 1024) {
        int lo = 0, hi = NB;
        while (hi - lo > 1) {
            int mid = (lo + hi) >> 1;
            if (lstart[mid] <= i) lo = mid; else hi = mid;
        }
        bin[gbase[lo] + (i - lstart[lo])] = stage[i];
    }
}

// ---------- Pass B: within-bucket counting sort -> node-sorted SoA + CSR + dinv ----------
__global__ __launch_bounds__(1024) void k_sort(const uint2* __restrict__ bin,
                                               const int* __restrict__ cursor,
                                               unsigned* __restrict__ ekey,
                                               half_t* __restrict__ ew16,
                                               int2* __restrict__ nodeptr2,
                                               float* __restrict__ dinv) {
    __shared__ int cnt[SZB];
    __shared__ float wdeg[SZB];
    __shared__ int ps[SZB];
    __shared__ int curp[SZB];
    __shared__ unsigned skey_st[CAP];   // 71.7 KB
    __shared__ half_t sw_st[CAP];       // 35.8 KB
    int b = blockIdx.x, tid = threadIdx.x;
    if (tid < SZB) { cnt[tid] = 0; wdeg[tid] = 0.0f; }
    __syncthreads();
    int s = b * CAP, e = cursor[b];
    int m = e - s;
    for (int i = s + tid; i < e; i += 1024) {
        uint2 u = bin[i];
        int cl = u.x & 511;
        atomicAdd(&cnt[cl], 1);
        atomicAdd(&wdeg[cl], __uint_as_float(u.y));
    }
    __syncthreads();
    if (tid < SZB) ps[tid] = cnt[tid];
    for (int off = 1; off < SZB; off <<= 1) {
        __syncthreads();
        int v = (tid < SZB && tid >= off) ? ps[tid - off] : 0;
        __syncthreads();
        if (tid < SZB) ps[tid] += v;
    }
    __syncthreads();
    if (tid < SZB) {
        int ex = ps[tid] - cnt[tid];
        curp[tid] = ex;
        int n = b * SZB + tid;
        if (n < NN) {
            nodeptr2[n] = make_int2(s + ex, s + ex + cnt[tid]);
            dinv[n] = rsqrtf(1.0f + wdeg[tid]);   // deg >= 1 (self-loop)
        }
    }
    __syncthreads();
    for (int i = s + tid; i < e; i += 1024) {
        uint2 u = bin[i];
        int cl = u.x & 511;
        int pos = atomicAdd(&curp[cl], 1);
        skey_st[pos] = u.x >> 9;
        sw_st[pos] = (half_t)__uint_as_float(u.y);
    }
    __syncthreads();
    for (int i = tid; i < m; i += 1024) {
        ekey[s + i] = skey_st[i];
        ew16[s + i] = sw_st[i];
    }
}

// ---------- Layer-1 transform: tt1 = fp16( dinv * (x @ W1) ) ----------
__global__ __launch_bounds__(256) void k_xform1(const float* __restrict__ x,
                                                const float* __restrict__ W,
                                                const float* __restrict__ dinv,
                                                half_t* __restrict__ tt) {
    __shared__ float Ws[F_IN * HID];
    for (int i = threadIdx.x; i < F_IN * HID; i += 256) Ws[i] = W[i];
    __syncthreads();
    int n = blockIdx.x * blockDim.x + threadIdx.x;
    if (n >= NN) return;
    float acc[HID];
#pragma unroll
    for (int j = 0; j < HID; j++) acc[j] = 0.0f;
    const float4* xp = (const float4*)(x + (size_t)n * F_IN);
#pragma unroll
    for (int k4 = 0; k4 < F_IN / 4; k4++) {
        float4 v = xp[k4];
        int k = k4 * 4;
#pragma unroll
        for (int j = 0; j < HID; j++) {
            acc[j] += v.x * Ws[(k + 0) * HID + j];
            acc[j] += v.y * Ws[(k + 1) * HID + j];
            acc[j] += v.z * Ws[(k + 2) * HID + j];
            acc[j] += v.w * Ws[(k + 3) * HID + j];
        }
    }
    float di = dinv[n];
    h4f* op = (h4f*)(tt + (size_t)n * HID);
#pragma unroll
    for (int g = 0; g < 4; g++) {
        h4f o;
        o.x = (half_t)(di * acc[g * 4 + 0]);
        o.y = (half_t)(di * acc[g * 4 + 1]);
        o.z = (half_t)(di * acc[g * 4 + 2]);
        o.w = (half_t)(di * acc[g * 4 + 3]);
        op[g] = o;
    }
}

// ---------- Fused aggregation + relu + next-layer transform ----------
// 4 lanes per node, 4 feats per lane; shuffle-free edge loop.
template <int DN>
__global__ __launch_bounds__(256) void k_aggf(const unsigned* __restrict__ ekey,
                                              const half_t* __restrict__ ew16,
                                              const int2* __restrict__ nptr,
                                              const half_t* __restrict__ tt_in,
                                              const float* __restrict__ bias,
                                              const float* __restrict__ dinv,
                                              const float* __restrict__ Wn,
                                              half_t* __restrict__ tt_out) {
    __shared__ float Ws[HID * DN];
    if (threadIdx.x < HID * DN) Ws[threadIdx.x] = Wn[threadIdx.x];
    __syncthreads();
    int tid = blockIdx.x * 256 + threadIdx.x;
    int n = tid >> 2;
    int l = tid & 3;
    if (n >= NN) return;
    int2 p = nptr[n];
    const h4f* ttp = (const h4f*)tt_in;
    h4f sv = ttp[n * 4 + l];
    float ax = 0.f, ay = 0.f, az = 0.f, aw = 0.f;
    int abase = p.x & ~3;
    for (int base = abase; base < p.y; base += 4) {
        int4 k4 = *(const int4*)(ekey + base);
        h4f w4 = *(const h4f*)(ew16 + base);
        bool ok0 = (base + 0 >= p.x) & (base + 0 < p.y);
        bool ok1 = (base + 1 >= p.x) & (base + 1 < p.y);
        bool ok2 = (base + 2 >= p.x) & (base + 2 < p.y);
        bool ok3 = (base + 3 >= p.x) & (base + 3 < p.y);
        float w0 = ok0 ? (float)w4.x : 0.f; int r0 = ok0 ? k4.x : 0;
        float w1 = ok1 ? (float)w4.y : 0.f; int r1 = ok1 ? k4.y : 0;
        float w2 = ok2 ? (float)w4.z : 0.f; int r2 = ok2 ? k4.z : 0;
        float w3 = ok3 ? (float)w4.w : 0.f; int r3 = ok3 ? k4.w : 0;
        h4f v0 = ttp[r0 * 4 + l];
        h4f v1 = ttp[r1 * 4 + l];
        h4f v2 = ttp[r2 * 4 + l];
        h4f v3 = ttp[r3 * 4 + l];
        ax += w0 * (float)v0.x; ay += w0 * (float)v0.y; az += w0 * (float)v0.z; aw += w0 * (float)v0.w;
        ax += w1 * (float)v1.x; ay += w1 * (float)v1.y; az += w1 * (float)v1.z; aw += w1 * (float)v1.w;
        ax += w2 * (float)v2.x; ay += w2 * (float)v2.y; az += w2 * (float)v2.z; aw += w2 * (float)v2.w;
        ax += w3 * (float)v3.x; ay += w3 * (float)v3.y; az += w3 * (float)v3.z; aw += w3 * (float)v3.w;
    }
    float di = dinv[n];
    const float4* b4p = (const float4*)bias;
    float4 b4 = b4p[l];
    float hreg[4];
    hreg[0] = fmaxf(b4.x + di * (ax + (float)sv.x), 0.f);
    hreg[1] = fmaxf(b4.y + di * (ay + (float)sv.y), 0.f);
    hreg[2] = fmaxf(b4.z + di * (az + (float)sv.z), 0.f);
    hreg[3] = fmaxf(b4.w + di * (aw + (float)sv.w), 0.f);
    if (DN == 16) {
        float ox = 0.f, oy = 0.f, oz = 0.f, ow = 0.f;
#pragma unroll
        for (int k = 0; k < HID; k++) {
            float hk = __shfl(hreg[k & 3], k >> 2, 4);
            const float4 wk = *(const float4*)&Ws[k * 16 + 4 * l];
            ox += hk * wk.x; oy += hk * wk.y; oz += hk * wk.z; ow += hk * wk.w;
        }
        h4f ov;
        ov.x = (half_t)(di * ox); ov.y = (half_t)(di * oy);
        ov.z = (half_t)(di * oz); ov.w = (half_t)(di * ow);
        ((h4f*)tt_out)[n * 4 + l] = ov;
    } else {
        float o = 0.f;
#pragma unroll
        for (int k = 0; k < HID; k++) {
            float hk = __shfl(hreg[k & 3], k >> 2, 4);
            o += hk * Ws[k * DN + l];
        }
        tt_out[(size_t)n * DN + l] = (half_t)(di * o);
    }
}

// ---------- Final aggregation (4 feats) + fused log-softmax ----------
__global__ __launch_bounds__(256) void k_agg4sm(const unsigned* __restrict__ ekey,
                                                const half_t* __restrict__ ew16,
                                                const int2* __restrict__ nptr,
                                                const half_t* __restrict__ tt,
                                                const float* __restrict__ bias,
                                                const float* __restrict__ dinv,
                                                float* __restrict__ out) {
    int tid = blockIdx.x * 256 + threadIdx.x;
    int n = tid >> 2;
    int l = tid & 3;
    if (n >= NN) return;
    int2 p = nptr[n];
    float self = (float)tt[n * 4 + l];
    float acc = 0.f;
    int abase = p.x & ~3;
    for (int base = abase; base < p.y; base += 4) {
        int4 k4 = *(const int4*)(ekey + base);
        h4f w4 = *(const h4f*)(ew16 + base);
        bool ok0 = (base + 0 >= p.x) & (base + 0 < p.y);
        bool ok1 = (base + 1 >= p.x) & (base + 1 < p.y);
        bool ok2 = (base + 2 >= p.x) & (base + 2 < p.y);
        bool ok3 = (base + 3 >= p.x) & (base + 3 < p.y);
        float w0 = ok0 ? (float)w4.x : 0.f; int r0 = ok0 ? k4.x : 0;
        float w1 = ok1 ? (float)w4.y : 0.f; int r1 = ok1 ? k4.y : 0;
        float w2 = ok2 ? (float)w4.z : 0.f; int r2 = ok2 ? k4.z : 0;
        float w3 = ok3 ? (float)w4.w : 0.f; int r3 = ok3 ? k4.w : 0;
        acc += w0 * (float)tt[r0 * 4 + l];
        acc += w1 * (float)tt[r1 * 4 + l];
        acc += w2 * (float)tt[r2 * 4 + l];
        acc += w3 * (float)tt[r3 * 4 + l];
    }
    float di = dinv[n];
    float logit = bias[l] + di * (acc + self);
    float m = logit;
    m = fmaxf(m, __shfl_xor(m, 1, 4));
    m = fmaxf(m, __shfl_xor(m, 2, 4));
    float ex = expf(logit - m);
    float s = ex;
    s += __shfl_xor(s, 1, 4);
    s += __shfl_xor(s, 2, 4);
    out[n * 4 + l] = logit - m - logf(s);
}

extern "C" void kernel_launch(void* const* d_in, const int* in_sizes, int n_in,
                              void* d_out, int out_size, void* d_ws, size_t ws_size,
                              hipStream_t stream) {
    const float* x  = (const float*)d_in[0];
    const int*   ei = (const int*)d_in[1];   // [2, E]: row then col
    const float* ew = (const float*)d_in[2];
    const float* W1 = (const float*)d_in[3];
    const float* b1 = (const float*)d_in[4];
    const float* W3 = (const float*)d_in[5];
    const float* b3 = (const float*)d_in[6];
    const float* W2 = (const float*)d_in[7];
    const float* b2 = (const float*)d_in[8];
    float* out = (float*)d_out;

    const int* row = ei;
    const int* col = ei + NE;

    const size_t NEP = (size_t)NB * CAP;   // padded edge count = 3,512,320
    // workspace layout (16B-aligned segments)
    char* ws = (char*)d_ws;
    size_t off = 0;
    float*    dinv     = (float*)(ws + off);    off += 400000;           // NN f32
    int2*     nodeptr2 = (int2*)(ws + off);     off += 800000;           // NN int2
    int*      cursor   = (int*)(ws + off);      off += 1024;             // NB ints
    unsigned* ekey     = (unsigned*)(ws + off); off += NEP * 4;          // 14.0 MB
    half_t*   ew16     = (half_t*)(ws + off);   off += NEP * 2;          // 7.0 MB
    uint2*    bin      = (uint2*)(ws + off);    off += NEP * 8;          // 28.1 MB
    half_t*   tt1      = (half_t*)(ws + off);   off += (size_t)NN * HID * 2;
    half_t*   tt2      = (half_t*)(ws + off);   off += (size_t)NN * HID * 2;
    half_t*   tt3      = (half_t*)(ws + off);   off += (size_t)NN * NC * 2;

    // Build node-sorted SoA edge structure (coarse-bucket bin, per-bucket sort)
    k_initcur<<<1, 256, 0, stream>>>(cursor);
    k_bin<<<NCH, 1024, 0, stream>>>(row, col, ew, cursor, bin);
    k_sort<<<NB, 1024, 0, stream>>>(bin, cursor, ekey, ew16, nodeptr2, dinv);

    int gN = (NN + 255) / 256;           // 391
    int gA = (NN * 4 + 255) / 256;       // 1563

    // Layer 1 transform, fused (agg+relu+matmul) x2, final agg+softmax
    k_xform1<<<gN, 256, 0, stream>>>(x, W1, dinv, tt1);
    k_aggf<HID><<<gA, 256, 0, stream>>>(ekey, ew16, nodeptr2, tt1, b1, dinv, W3, tt2);
    k_aggf<NC><<<gA, 256, 0, stream>>>(ekey, ew16, nodeptr2, tt2, b3, dinv, W2, tt3);
    k_agg4sm<<<gA, 256, 0, stream>>>(ekey, ew16, nodeptr2, tt3, b2, dinv, out);
}